// Round 1
// baseline (1574.694 us; speedup 1.0000x reference)
//
#include <hip/hip_runtime.h>
#include <hip/hip_bf16.h>
#include <math.h>

// ---------------- constants ----------------
#define BSZ      8
#define TPREF    6144
#define CIN      8
#define DMODEL   256
#define DINNER   512
#define DSTATE   32
#define NHEADS   8
#define HEADDIM  64
#define CONVDIM  576
#define DPROJ    1096
#define NTOK     512
#define NVIS     384     // unmasked tokens
#define TBWD     128     // bwd truncation (tokens 384..511 reversed)

__device__ __forceinline__ float silu_f(float x) { return x / (1.f + expf(-x)); }

// ---------------- small prep kernels ----------------

// Wt[(k*256+c)*256 + o] = patch_w[(o*256+c)*16 + k]
__global__ void transpose_pw_kernel(const float* __restrict__ pw, float* __restrict__ Wt) {
    int idx = blockIdx.x * 256 + threadIdx.x;           // 256*256*16 = 1048576
    if (idx >= 256 * 256 * 16) return;
    int k = idx & 15, c = (idx >> 4) & 255, o = idx >> 12;
    Wt[((k << 8) + c) * 256 + o] = pw[idx];
}

// aux_bias[b,o] = silu(aux_b[o] + sum_i y_aux[b,i]*aux_w[i,o])
__global__ void aux_kernel(const float* __restrict__ y_aux, const float* __restrict__ aux_w,
                           const float* __restrict__ aux_b, float* __restrict__ out) {
    int b = blockIdx.x, o = threadIdx.x;
    float acc = aux_b[o];
    #pragma unroll
    for (int i = 0; i < 16; i++) acc += y_aux[b * 16 + i] * aux_w[i * 256 + o];
    out[b * 256 + o] = silu_f(acc);
}

// pre-conv (K=5, pad 2) + silu.  out layout (B, 6144, 256). Only t<6144 needed.
__global__ void preconv_kernel(const float* __restrict__ xp, const float* __restrict__ w,
                               const float* __restrict__ bias, float* __restrict__ out) {
    int blk = blockIdx.x;                       // B * (6144/16)
    int b  = blk / (TPREF / 16);
    int t0 = (blk % (TPREF / 16)) * 16;
    int o  = threadIdx.x;                       // 256
    __shared__ float xs[20][CIN];               // t0-2 .. t0+17
    if (o < 160) {
        int k = o / 8, i = o % 8;
        int tt = t0 - 2 + k;
        xs[k][i] = (tt >= 0 && tt < TPREF) ? xp[(b * TPREF + tt) * CIN + i] : 0.f;
    }
    float wreg[40];
    const float* wo = w + o * 40;               // pre_conv_w[o, i, k]
    #pragma unroll
    for (int j = 0; j < 40; j++) wreg[j] = wo[j];
    float bo = bias[o];
    __syncthreads();
    for (int dt_ = 0; dt_ < 16; dt_++) {
        float acc = bo;
        #pragma unroll
        for (int i = 0; i < 8; i++)
            #pragma unroll
            for (int k = 0; k < 5; k++)
                acc += wreg[i * 5 + k] * xs[dt_ + k][i];
        out[(b * TPREF + t0 + dt_) * 256 + o] = silu_f(acc);
    }
}

// h_f[b,tok,o]; h_b[b,511-tok,o] for tok>=384
__global__ void assemble_kernel(const float* __restrict__ Cp, const float* __restrict__ mtok,
                                const float* __restrict__ aux, float* __restrict__ h_f,
                                float* __restrict__ h_b) {
    int idx = blockIdx.x * 256 + threadIdx.x;   // B*512*256
    if (idx >= BSZ * NTOK * DMODEL) return;
    int o = idx & 255, tok = (idx >> 8) & 511, b = idx >> 17;
    float v = (tok < NVIS) ? Cp[(b * NVIS + tok) * 256 + o] : mtok[o];
    v += aux[b * 256 + o];
    h_f[idx] = v;
    if (tok >= NVIS) h_b[(b * TBWD + (NTOK - 1 - tok)) * 256 + o] = v;
}

// ---------------- generic fp32 GEMM ----------------
// C[m,n] = op( sum_k A[row_off(m)+k] * B[k*ldb+n] )
// row_off(m) = (m/rdiv)*rso + (m%rdiv)*rsi.  flags: 1=add bias[n], 2=accumulate into C.
// M must be a multiple of 64; K a multiple of 16.
__global__ __launch_bounds__(256) void gemm_f32(
    const float* __restrict__ A, const float* __restrict__ B,
    const float* __restrict__ bias, float* __restrict__ C,
    int M, int N, int K, int rdiv, long rso, long rsi,
    int ldb, int ldc, int flags) {
    __shared__ float As[16][68];
    __shared__ float Bs[16][64];
    int tid = threadIdx.x;
    int n0 = blockIdx.x * 64;
    int m0 = blockIdx.y * 64;
    int am = tid >> 4, ak = tid & 15;
    long aoff[4];
    #pragma unroll
    for (int l = 0; l < 4; l++) {
        int m = m0 + am + l * 16;
        aoff[l] = (long)(m / rdiv) * rso + (long)(m % rdiv) * rsi + ak;
    }
    int bn = tid & 63, bk0 = tid >> 6;
    int ty = tid >> 4, tx = tid & 15;
    float acc[4][4] = {};
    for (int k0 = 0; k0 < K; k0 += 16) {
        #pragma unroll
        for (int l = 0; l < 4; l++)
            As[ak][am + l * 16] = A[aoff[l] + k0];
        #pragma unroll
        for (int l = 0; l < 4; l++) {
            int kk = bk0 + l * 4;
            int gn = n0 + bn;
            Bs[kk][bn] = (gn < N) ? B[(long)(k0 + kk) * ldb + gn] : 0.f;
        }
        __syncthreads();
        #pragma unroll
        for (int kk = 0; kk < 16; kk++) {
            float a[4], bb[4];
            #pragma unroll
            for (int i = 0; i < 4; i++) a[i] = As[kk][ty * 4 + i];
            #pragma unroll
            for (int j = 0; j < 4; j++) bb[j] = Bs[kk][tx * 4 + j];
            #pragma unroll
            for (int i = 0; i < 4; i++)
                #pragma unroll
                for (int j = 0; j < 4; j++) acc[i][j] += a[i] * bb[j];
        }
        __syncthreads();
    }
    #pragma unroll
    for (int i = 0; i < 4; i++) {
        int gm = m0 + ty * 4 + i;
        #pragma unroll
        for (int j = 0; j < 4; j++) {
            int gn = n0 + tx * 4 + j;
            if (gn < N) {
                float v = acc[i][j];
                if (flags & 1) v += bias[gn];
                long ci = (long)gm * ldc + gn;
                if (flags & 2) v += C[ci];
                C[ci] = v;
            }
        }
    }
}

// ---------------- mamba block kernels ----------------

// rmsnorm over 256 (one 64-lane wave per row)
__global__ void rmsnorm256_kernel(const float* __restrict__ x, const float* __restrict__ w,
                                  float* __restrict__ out) {
    long row = blockIdx.x;
    int tid = threadIdx.x;  // 64
    const float4* xr = (const float4*)(x + row * 256);
    float4 v = xr[tid];
    float ss = v.x * v.x + v.y * v.y + v.z * v.z + v.w * v.w;
    #pragma unroll
    for (int off = 32; off >= 1; off >>= 1) ss += __shfl_xor(ss, off);
    float rs = rsqrtf(ss * (1.f / 256.f) + 1e-5f);
    float4 wv = ((const float4*)w)[tid];
    float4 o = make_float4(v.x * rs * wv.x, v.y * rs * wv.y, v.z * rs * wv.z, v.w * rs * wv.w);
    ((float4*)(out + row * 256))[tid] = o;
}

// dt = softplus(zx[...,1088+h] + dtbias[h])
__global__ void dt_kernel(const float* __restrict__ zx, const float* __restrict__ dtbias,
                          float* __restrict__ dtb, int M) {
    int idx = blockIdx.x * 256 + threadIdx.x;
    if (idx >= M * NHEADS) return;
    int h = idx & 7, row = idx >> 3;
    float x = zx[(long)row * DPROJ + 1088 + h] + dtbias[h];
    dtb[idx] = (x > 20.f) ? x : log1pf(expf(x));
}

// causal depthwise conv (k=4) + bias + silu over the 576 xBC channels of zx
__global__ void dwconv_kernel(const float* __restrict__ zx, const float* __restrict__ cw,
                              const float* __restrict__ cb, float* __restrict__ xbc,
                              int T, int M) {
    int idx = blockIdx.x * 256 + threadIdx.x;
    if (idx >= M * CONVDIM) return;
    int c = idx % CONVDIM;
    int row = idx / CONVDIM;
    int t = row % T;
    const float* base = zx + (long)row * DPROJ + DINNER + c;
    float acc = cb[c];
    #pragma unroll
    for (int k = 0; k < 4; k++) {
        int tt = t - 3 + k;
        if (tt >= 0) acc += cw[c * 4 + k] * base[(long)(k - 3) * DPROJ];
    }
    xbc[idx] = silu_f(acc);
}

// sequential selective scan, one block per (head, batch). y includes +D*x.
__global__ void scan_kernel(const float* __restrict__ xbc, const float* __restrict__ dtb,
                            const float* __restrict__ Alog, const float* __restrict__ Dp,
                            float* __restrict__ ysD, int T) {
    int hd = blockIdx.x;    // 8
    int b  = blockIdx.y;    // 8
    int tid = threadIdx.x;  // 256
    int p = tid >> 2, nq = tid & 3;
    float A  = -expf(Alog[hd]);
    float Dh = Dp[hd];
    float s[8];
    #pragma unroll
    for (int j = 0; j < 8; j++) s[j] = 0.f;
    const int nbase = DINNER + nq * 8;
    for (int t = 0; t < T; t++) {
        long row = (long)(b * T + t);
        float dtv = dtb[row * NHEADS + hd];
        const float* xr = xbc + row * CONVDIM;
        float dA = expf(dtv * A);
        float xv = xr[hd * HEADDIM + p];
        float coef = dtv * xv;
        float acc = 0.f;
        #pragma unroll
        for (int j = 0; j < 8; j++) {
            float Bn = xr[nbase + j];
            float Cn = xr[nbase + DSTATE + j];
            s[j] = s[j] * dA + coef * Bn;
            acc += s[j] * Cn;
        }
        acc += __shfl_xor(acc, 1);
        acc += __shfl_xor(acc, 2);
        if (nq == 0) ysD[row * DINNER + hd * HEADDIM + p] = acc + Dh * xv;
    }
}

// y2 = rmsnorm(ysD * silu(z), gnorm) over 512 dims; z = zx[...,:512]
__global__ void gatednorm_kernel(const float* __restrict__ ysD, const float* __restrict__ zx,
                                 const float* __restrict__ gw, float* __restrict__ y2) {
    long row = blockIdx.x;
    int tid = threadIdx.x;  // 64 lanes x 8 elems
    const float* yr = ysD + row * DINNER + tid * 8;
    const float* zr = zx + row * DPROJ + tid * 8;
    float g[8];
    float ss = 0.f;
    #pragma unroll
    for (int j = 0; j < 8; j++) {
        float z = zr[j];
        float gg = yr[j] * silu_f(z);
        g[j] = gg;
        ss += gg * gg;
    }
    #pragma unroll
    for (int off = 32; off >= 1; off >>= 1) ss += __shfl_xor(ss, off);
    float rs = rsqrtf(ss * (1.f / 512.f) + 1e-5f);
    float* o = y2 + row * DINNER + tid * 8;
    const float* gwp = gw + tid * 8;
    #pragma unroll
    for (int j = 0; j < 8; j++) o[j] = g[j] * rs * gwp[j];
}

// hcat[b,j,:] = concat(h_f[b,384+j,:], h_b[b,127-j,:])
__global__ void hcat_kernel(const float* __restrict__ h_f, const float* __restrict__ h_b,
                            float* __restrict__ hc) {
    int idx = blockIdx.x * 256 + threadIdx.x;   // 8*128*512
    if (idx >= BSZ * TBWD * DINNER) return;
    int c = idx & 511, j = (idx >> 9) & 127, b = idx >> 16;
    float v = (c < 256) ? h_f[(b * NTOK + NVIS + j) * 256 + c]
                        : h_b[(b * TBWD + (TBWD - 1 - j)) * 256 + (c - 256)];
    hc[idx] = v;
}

// ---------------- launch ----------------
extern "C" void kernel_launch(void* const* d_in, const int* in_sizes, int n_in,
                              void* d_out, int out_size, void* d_ws, size_t ws_size,
                              hipStream_t stream) {
    const float* x_prefix    = (const float*)d_in[0];
    const float* y_aux       = (const float*)d_in[1];
    const float* pre_conv_w  = (const float*)d_in[2];
    const float* pre_conv_b  = (const float*)d_in[3];
    const float* patch_w     = (const float*)d_in[4];
    const float* patch_b     = (const float*)d_in[5];
    const float* mask_token  = (const float*)d_in[6];
    const float* aux_w       = (const float*)d_in[7];
    const float* aux_b       = (const float*)d_in[8];
    const float* patch_out_w = (const float*)d_in[9];
    const float* patch_out_b = (const float*)d_in[10];
    // dir 0 = fwd (d_in[11..19]), dir 1 = bwd (d_in[20..28])
    const float* w_norm[2]   = {(const float*)d_in[11], (const float*)d_in[20]};
    const float* w_inproj[2] = {(const float*)d_in[12], (const float*)d_in[21]};
    const float* w_convw[2]  = {(const float*)d_in[13], (const float*)d_in[22]};
    const float* w_convb[2]  = {(const float*)d_in[14], (const float*)d_in[23]};
    const float* w_dtb[2]    = {(const float*)d_in[15], (const float*)d_in[24]};
    const float* w_alog[2]   = {(const float*)d_in[16], (const float*)d_in[25]};
    const float* w_D[2]      = {(const float*)d_in[17], (const float*)d_in[26]};
    const float* w_gnorm[2]  = {(const float*)d_in[18], (const float*)d_in[27]};
    const float* w_outproj[2]= {(const float*)d_in[19], (const float*)d_in[28]};

    float* ws = (float*)d_ws;
    float* Wt   = ws; ws += 1048576;     // 16*256 x 256 transposed patch weight
    float* auxb = ws; ws += 2048;        // (8,256)
    float* xpre = ws; ws += 12582912;    // (8,6144,256)
    float* Cp   = ws; ws += 786432;      // (3072,256) patch gemm out
    float* h_f  = ws; ws += 1048576;     // (8,512,256)
    float* h_b  = ws; ws += 262144;      // (8,128,256)
    float* u    = ws; ws += 1048576;     // (M,256)
    float* zx   = ws; ws += 4489216;     // (M,1096)
    float* dtb  = ws; ws += 32768;       // (M,8)
    float* xbc  = ws; ws += 2359296;     // (M,576)
    float* ysD  = ws; ws += 2097152;     // (M,512)
    float* y2   = ws; ws += 2097152;     // (M,512)
    float* hct  = ws; ws += 524288;      // (8,128,512)

    transpose_pw_kernel<<<4096, 256, 0, stream>>>(patch_w, Wt);
    aux_kernel<<<BSZ, 256, 0, stream>>>(y_aux, aux_w, aux_b, auxb);
    preconv_kernel<<<BSZ * (TPREF / 16), 256, 0, stream>>>(x_prefix, pre_conv_w, pre_conv_b, xpre);
    // patch conv as GEMM: M=3072, N=256, K=4096; A row = xpre[b, 16*tok : 16*tok+16, :]
    gemm_f32<<<dim3(4, 48), 256, 0, stream>>>(xpre, Wt, patch_b, Cp,
                                              3072, 256, 4096,
                                              NVIS, (long)TPREF * 256, (long)16 * 256,
                                              256, 256, 1);
    assemble_kernel<<<(BSZ * NTOK * DMODEL) / 256, 256, 0, stream>>>(Cp, mask_token, auxb, h_f, h_b);

    for (int dir = 0; dir < 2; dir++) {
        float* h = (dir == 0) ? h_f : h_b;
        int T = (dir == 0) ? NTOK : TBWD;   // bwd truncated: only first 128 reversed steps needed
        int M = BSZ * T;
        for (int i = 0; i < 2; i++) {
            rmsnorm256_kernel<<<M, 64, 0, stream>>>(h, w_norm[dir] + i * 256, u);
            gemm_f32<<<dim3(18, M / 64), 256, 0, stream>>>(u, w_inproj[dir] + (long)i * 256 * DPROJ,
                                                           nullptr, zx,
                                                           M, DPROJ, 256,
                                                           1 << 30, 0, 256, DPROJ, DPROJ, 0);
            dt_kernel<<<(M * NHEADS + 255) / 256, 256, 0, stream>>>(zx, w_dtb[dir] + i * 8, dtb, M);
            dwconv_kernel<<<(M * CONVDIM + 255) / 256, 256, 0, stream>>>(
                zx, w_convw[dir] + i * CONVDIM * 4, w_convb[dir] + i * CONVDIM, xbc, T, M);
            scan_kernel<<<dim3(NHEADS, BSZ), 256, 0, stream>>>(xbc, dtb, w_alog[dir] + i * 8,
                                                               w_D[dir] + i * 8, ysD, T);
            gatednorm_kernel<<<M, 64, 0, stream>>>(ysD, zx, w_gnorm[dir] + i * DINNER, y2);
            gemm_f32<<<dim3(4, M / 64), 256, 0, stream>>>(y2, w_outproj[dir] + (long)i * DINNER * DMODEL,
                                                          nullptr, h,
                                                          M, DMODEL, DINNER,
                                                          1 << 30, 0, DINNER, DMODEL, DMODEL, 2);
        }
    }

    hcat_kernel<<<(BSZ * TBWD * DINNER) / 256, 256, 0, stream>>>(h_f, h_b, hct);
    // final patch_out GEMM writes directly into d_out:
    // out[b,tt,c] flat == patch_pred[b, j, rem] flat because 6144*8 == 384*128
    gemm_f32<<<dim3(2, 16), 256, 0, stream>>>(hct, patch_out_w, patch_out_b, (float*)d_out,
                                              BSZ * TBWD, 128, DINNER,
                                              1 << 30, 0, DINNER, 128, 128, 1);
}

// Round 2
// 987.501 us; speedup vs baseline: 1.5946x; 1.5946x over previous
//
#include <hip/hip_runtime.h>
#include <hip/hip_bf16.h>
#include <math.h>

// ---------------- constants ----------------
#define BSZ      8
#define TPREF    6144
#define CIN      8
#define DMODEL   256
#define DINNER   512
#define DSTATE   32
#define NHEADS   8
#define HEADDIM  64
#define CONVDIM  576
#define DPROJ    1096
#define NTOK     512
#define NVIS     384     // unmasked tokens
#define TBWD     128     // bwd truncation (tokens 384..511 reversed)

typedef float f32x4 __attribute__((ext_vector_type(4)));
typedef __bf16 bf16x8 __attribute__((ext_vector_type(8)));

__device__ __forceinline__ float silu_f(float x) { return x / (1.f + expf(-x)); }

#define ASYNC16(gp, lp) \
    __builtin_amdgcn_global_load_lds((const __attribute__((address_space(1))) void*)(gp), \
                                     (__attribute__((address_space(3))) void*)(lp), 16, 0, 0)

// ---------------- bf16 MFMA GEMM (NT layout: C[m,n] = sum_k A[m,k]*Bt[n,k]) ----------------
// 128x128 tile, 256 threads (4 waves, 2x2), 16x16x32 MFMA, BK=32, global_load_lds staging.
// grid = (Npad/128, M/128, splitK). flags: bit1 -> atomicAdd into C (split-K / residual),
// else plain store (+bias if non-null). M % 128 == 0; K/gridDim.z % 32 == 0; rows 16B-aligned.
__global__ __launch_bounds__(256) void gemm_mfma(
    const __bf16* __restrict__ A, const __bf16* __restrict__ Bt,
    float* __restrict__ C, const float* __restrict__ bias,
    int N, int K, int ldc, int flags) {
    __shared__ char sm[16384];                  // A tile 8KB | B tile 8KB
    int tid = threadIdx.x;
    int m0 = blockIdx.y * 128, n0 = blockIdx.x * 128;
    int klen = K / gridDim.z;
    int kbeg = blockIdx.z * klen;
    int w = tid >> 6, l = tid & 63;
    int wm = w >> 1, wn = w & 1;
    int lm = l & 15, q = l >> 4;

    f32x4 acc[4][4];
    #pragma unroll
    for (int i = 0; i < 4; i++)
        #pragma unroll
        for (int j = 0; j < 4; j++) acc[i][j] = (f32x4)0.f;

    for (int k0 = 0; k0 < klen; k0 += 32) {
        int kb = kbeg + k0;
        #pragma unroll
        for (int i = 0; i < 2; i++) {
            int s = i * 256 + tid;
            ASYNC16(A + (size_t)(m0 + (s >> 2)) * K + kb + (s & 3) * 8, sm + s * 16);
        }
        #pragma unroll
        for (int i = 0; i < 2; i++) {
            int s = i * 256 + tid;
            ASYNC16(Bt + (size_t)(n0 + (s >> 2)) * K + kb + (s & 3) * 8, sm + 8192 + s * 16);
        }
        __syncthreads();
        bf16x8 af[4], bfr[4];
        #pragma unroll
        for (int mf = 0; mf < 4; mf++)
            af[mf] = *(const bf16x8*)(sm + (wm * 64 + mf * 16 + lm) * 64 + q * 16);
        #pragma unroll
        for (int nf = 0; nf < 4; nf++)
            bfr[nf] = *(const bf16x8*)(sm + 8192 + (wn * 64 + nf * 16 + lm) * 64 + q * 16);
        #pragma unroll
        for (int mf = 0; mf < 4; mf++)
            #pragma unroll
            for (int nf = 0; nf < 4; nf++)
                acc[mf][nf] = __builtin_amdgcn_mfma_f32_16x16x32_bf16(af[mf], bfr[nf], acc[mf][nf], 0, 0, 0);
        __syncthreads();
    }

    #pragma unroll
    for (int mf = 0; mf < 4; mf++) {
        int mbase = m0 + wm * 64 + mf * 16 + q * 4;
        #pragma unroll
        for (int nf = 0; nf < 4; nf++) {
            int n = n0 + wn * 64 + nf * 16 + lm;
            if (n < N) {
                #pragma unroll
                for (int r = 0; r < 4; r++) {
                    float v = acc[mf][nf][r];
                    size_t ci = (size_t)(mbase + r) * ldc + n;
                    if (flags & 2) atomicAdd(C + ci, v);
                    else C[ci] = v + (bias ? bias[n] : 0.f);
                }
            }
        }
    }
}

// ---------------- prep / conversion kernels ----------------

// generic: src fp32 [K][N] row-major -> dst bf16 [n][k] (K-contiguous rows)
__global__ void tconv_kernel(const float* __restrict__ src, __bf16* __restrict__ dst, int K, int N) {
    int idx = blockIdx.x * 256 + threadIdx.x;
    if (idx >= K * N) return;
    int k = idx / N, n = idx % N;
    dst[(size_t)n * K + k] = (__bf16)src[idx];
}

// patch_w [o][c][k16] fp32 -> WtT bf16 [o][k16*256 + c]  (row o is K=4096 contiguous)
__global__ void patchw_kernel(const float* __restrict__ pw, __bf16* __restrict__ dst) {
    int idx = blockIdx.x * 256 + threadIdx.x;           // 1048576
    if (idx >= 256 * 256 * 16) return;
    int k = idx & 15, c = (idx >> 4) & 255, o = idx >> 12;
    dst[(size_t)o * 4096 + k * 256 + c] = (__bf16)pw[idx];
}

// aux_bias[b,o] = silu(aux_b[o] + sum_i y_aux[b,i]*aux_w[i,o])
__global__ void aux_kernel(const float* __restrict__ y_aux, const float* __restrict__ aux_w,
                           const float* __restrict__ aux_b, float* __restrict__ out) {
    int b = blockIdx.x, o = threadIdx.x;
    float acc = aux_b[o];
    #pragma unroll
    for (int i = 0; i < 16; i++) acc += y_aux[b * 16 + i] * aux_w[i * 256 + o];
    out[b * 256 + o] = silu_f(acc);
}

// pre-conv (K=5, pad 2) + silu -> A_patch bf16, row (b*384+tok) = 16x256 patch window
__global__ void preconv_kernel(const float* __restrict__ xp, const float* __restrict__ w,
                               const float* __restrict__ bias, __bf16* __restrict__ out) {
    int blk = blockIdx.x;                       // B * 384
    int b  = blk / (TPREF / 16);
    int t0 = (blk % (TPREF / 16)) * 16;
    int o  = threadIdx.x;                       // 256
    __shared__ float xs[20][CIN];               // t0-2 .. t0+17
    if (o < 160) {
        int k = o / 8, i = o % 8;
        int tt = t0 - 2 + k;
        xs[k][i] = (tt >= 0 && tt < TPREF) ? xp[(b * TPREF + tt) * CIN + i] : 0.f;
    }
    float wreg[40];
    const float* wo = w + o * 40;               // pre_conv_w[o, i, k]
    #pragma unroll
    for (int j = 0; j < 40; j++) wreg[j] = wo[j];
    float bo = bias[o];
    __syncthreads();
    size_t rbase = (size_t)blk * 4096;
    for (int dt_ = 0; dt_ < 16; dt_++) {
        float acc = bo;
        #pragma unroll
        for (int i = 0; i < 8; i++)
            #pragma unroll
            for (int k = 0; k < 5; k++)
                acc += wreg[i * 5 + k] * xs[dt_ + k][i];
        out[rbase + dt_ * 256 + o] = (__bf16)silu_f(acc);
    }
}

// h_f[b,tok,o] (+patch bias); h_b[b,511-tok,o] for tok>=384
__global__ void assemble_kernel(const float* __restrict__ Cp, const float* __restrict__ pb,
                                const float* __restrict__ mtok, const float* __restrict__ aux,
                                float* __restrict__ h_f, float* __restrict__ h_b) {
    int idx = blockIdx.x * 256 + threadIdx.x;   // B*512*256
    if (idx >= BSZ * NTOK * DMODEL) return;
    int o = idx & 255, tok = (idx >> 8) & 511, b = idx >> 17;
    float v = (tok < NVIS) ? (Cp[(b * NVIS + tok) * 256 + o] + pb[o]) : mtok[o];
    v += aux[b * 256 + o];
    h_f[idx] = v;
    if (tok >= NVIS) h_b[(b * TBWD + (NTOK - 1 - tok)) * 256 + o] = v;
}

// d_out init with patch_out bias
__global__ void biasout_kernel(const float* __restrict__ pb, float* __restrict__ out) {
    int idx = blockIdx.x * 256 + threadIdx.x;   // 1024*128
    if (idx >= BSZ * TBWD * 128) return;
    out[idx] = pb[idx & 127];
}

// ---------------- mamba block kernels ----------------

// rmsnorm over 256 -> bf16 (one 64-lane wave per row)
__global__ void rmsnorm256_kernel(const float* __restrict__ x, const float* __restrict__ w,
                                  __bf16* __restrict__ out) {
    long row = blockIdx.x;
    int tid = threadIdx.x;  // 64
    const float4* xr = (const float4*)(x + row * 256);
    float4 v = xr[tid];
    float ss = v.x * v.x + v.y * v.y + v.z * v.z + v.w * v.w;
    #pragma unroll
    for (int off = 32; off >= 1; off >>= 1) ss += __shfl_xor(ss, off);
    float rs = rsqrtf(ss * (1.f / 256.f) + 1e-5f);
    float4 wv = ((const float4*)w)[tid];
    __bf16* o = out + row * 256 + tid * 4;
    o[0] = (__bf16)(v.x * rs * wv.x);
    o[1] = (__bf16)(v.y * rs * wv.y);
    o[2] = (__bf16)(v.z * rs * wv.z);
    o[3] = (__bf16)(v.w * rs * wv.w);
}

// dt = softplus(zx[...,1088+h] + dtbias[h])
__global__ void dt_kernel(const float* __restrict__ zx, const float* __restrict__ dtbias,
                          float* __restrict__ dtb, int M) {
    int idx = blockIdx.x * 256 + threadIdx.x;
    if (idx >= M * NHEADS) return;
    int h = idx & 7, row = idx >> 3;
    float x = zx[(long)row * DPROJ + 1088 + h] + dtbias[h];
    dtb[idx] = (x > 20.f) ? x : log1pf(expf(x));
}

// causal depthwise conv (k=4) + bias + silu over the 576 xBC channels of zx
__global__ void dwconv_kernel(const float* __restrict__ zx, const float* __restrict__ cw,
                              const float* __restrict__ cb, float* __restrict__ xbc,
                              int T, int M) {
    int idx = blockIdx.x * 256 + threadIdx.x;
    if (idx >= M * CONVDIM) return;
    int c = idx % CONVDIM;
    int row = idx / CONVDIM;
    int t = row % T;
    const float* base = zx + (long)row * DPROJ + DINNER + c;
    float acc = cb[c];
    #pragma unroll
    for (int k = 0; k < 4; k++) {
        int tt = t - 3 + k;
        if (tt >= 0) acc += cw[c * 4 + k] * base[(long)(k - 3) * DPROJ];
    }
    xbc[idx] = silu_f(acc);
}

// sequential selective scan, one block per (head, batch). y includes +D*x.
__global__ void scan_kernel(const float* __restrict__ xbc, const float* __restrict__ dtb,
                            const float* __restrict__ Alog, const float* __restrict__ Dp,
                            float* __restrict__ ysD, int T) {
    int hd = blockIdx.x;    // 8
    int b  = blockIdx.y;    // 8
    int tid = threadIdx.x;  // 256
    int p = tid >> 2, nq = tid & 3;
    float A  = -expf(Alog[hd]);
    float Dh = Dp[hd];
    float s[8];
    #pragma unroll
    for (int j = 0; j < 8; j++) s[j] = 0.f;
    const int nbase = DINNER + nq * 8;
    for (int t = 0; t < T; t++) {
        long row = (long)(b * T + t);
        float dtv = dtb[row * NHEADS + hd];
        const float* xr = xbc + row * CONVDIM;
        float dA = expf(dtv * A);
        float xv = xr[hd * HEADDIM + p];
        float coef = dtv * xv;
        float acc = 0.f;
        #pragma unroll
        for (int j = 0; j < 8; j++) {
            float Bn = xr[nbase + j];
            float Cn = xr[nbase + DSTATE + j];
            s[j] = s[j] * dA + coef * Bn;
            acc += s[j] * Cn;
        }
        acc += __shfl_xor(acc, 1);
        acc += __shfl_xor(acc, 2);
        if (nq == 0) ysD[row * DINNER + hd * HEADDIM + p] = acc + Dh * xv;
    }
}

// y2 = rmsnorm(ysD * silu(z), gnorm) over 512 dims -> bf16; z = zx[...,:512]
__global__ void gatednorm_kernel(const float* __restrict__ ysD, const float* __restrict__ zx,
                                 const float* __restrict__ gw, __bf16* __restrict__ y2) {
    long row = blockIdx.x;
    int tid = threadIdx.x;  // 64 lanes x 8 elems
    const float* yr = ysD + row * DINNER + tid * 8;
    const float* zr = zx + row * DPROJ + tid * 8;
    float g[8];
    float ss = 0.f;
    #pragma unroll
    for (int j = 0; j < 8; j++) {
        float z = zr[j];
        float gg = yr[j] * silu_f(z);
        g[j] = gg;
        ss += gg * gg;
    }
    #pragma unroll
    for (int off = 32; off >= 1; off >>= 1) ss += __shfl_xor(ss, off);
    float rs = rsqrtf(ss * (1.f / 512.f) + 1e-5f);
    __bf16* o = y2 + row * DINNER + tid * 8;
    const float* gwp = gw + tid * 8;
    #pragma unroll
    for (int j = 0; j < 8; j++) o[j] = (__bf16)(g[j] * rs * gwp[j]);
}

// hcat[b,j,:] = concat(h_f[b,384+j,:], h_b[b,127-j,:]) -> bf16
__global__ void hcat_kernel(const float* __restrict__ h_f, const float* __restrict__ h_b,
                            __bf16* __restrict__ hc) {
    int idx = blockIdx.x * 256 + threadIdx.x;   // 8*128*512
    if (idx >= BSZ * TBWD * DINNER) return;
    int c = idx & 511, j = (idx >> 9) & 127, b = idx >> 16;
    float v = (c < 256) ? h_f[(b * NTOK + NVIS + j) * 256 + c]
                        : h_b[(b * TBWD + (TBWD - 1 - j)) * 256 + (c - 256)];
    hc[idx] = (__bf16)v;
}

// ---------------- launch ----------------
extern "C" void kernel_launch(void* const* d_in, const int* in_sizes, int n_in,
                              void* d_out, int out_size, void* d_ws, size_t ws_size,
                              hipStream_t stream) {
    const float* x_prefix    = (const float*)d_in[0];
    const float* y_aux       = (const float*)d_in[1];
    const float* pre_conv_w  = (const float*)d_in[2];
    const float* pre_conv_b  = (const float*)d_in[3];
    const float* patch_w     = (const float*)d_in[4];
    const float* patch_b     = (const float*)d_in[5];
    const float* mask_token  = (const float*)d_in[6];
    const float* aux_w       = (const float*)d_in[7];
    const float* aux_b       = (const float*)d_in[8];
    const float* patch_out_w = (const float*)d_in[9];
    const float* patch_out_b = (const float*)d_in[10];
    const float* w_norm[2]   = {(const float*)d_in[11], (const float*)d_in[20]};
    const float* w_inproj[2] = {(const float*)d_in[12], (const float*)d_in[21]};
    const float* w_convw[2]  = {(const float*)d_in[13], (const float*)d_in[22]};
    const float* w_convb[2]  = {(const float*)d_in[14], (const float*)d_in[23]};
    const float* w_dtb[2]    = {(const float*)d_in[15], (const float*)d_in[24]};
    const float* w_alog[2]   = {(const float*)d_in[16], (const float*)d_in[25]};
    const float* w_D[2]      = {(const float*)d_in[17], (const float*)d_in[26]};
    const float* w_gnorm[2]  = {(const float*)d_in[18], (const float*)d_in[27]};
    const float* w_outproj[2]= {(const float*)d_in[19], (const float*)d_in[28]};

    char* p = (char*)d_ws;
    auto alloc = [&](size_t bytes) { char* r = p; p += (bytes + 255) & ~255ULL; return r; };
    __bf16* A_patch  = (__bf16*)alloc((size_t)3072 * 4096 * 2);
    __bf16* WtT      = (__bf16*)alloc((size_t)256 * 4096 * 2);
    __bf16* inprojT  = (__bf16*)alloc((size_t)4 * 1152 * 256 * 2);   // [dir*2+layer][npad=1152][256]
    __bf16* outprojT = (__bf16*)alloc((size_t)4 * 256 * 512 * 2);    // [..][256][512]
    __bf16* poT      = (__bf16*)alloc((size_t)128 * 512 * 2);
    float*  auxb     = (float*)alloc(8 * 256 * 4);
    float*  Cp       = (float*)alloc((size_t)3072 * 256 * 4);
    float*  h_f      = (float*)alloc((size_t)BSZ * NTOK * DMODEL * 4);
    float*  h_b      = (float*)alloc((size_t)BSZ * TBWD * DMODEL * 4);
    __bf16* u        = (__bf16*)alloc((size_t)4096 * 256 * 2);
    float*  zx       = (float*)alloc((size_t)4096 * DPROJ * 4);
    float*  dtb      = (float*)alloc((size_t)4096 * 8 * 4);
    float*  xbc      = (float*)alloc((size_t)4096 * CONVDIM * 4);
    float*  ysD      = (float*)alloc((size_t)4096 * DINNER * 4);
    __bf16* y2       = (__bf16*)alloc((size_t)4096 * DINNER * 2);
    __bf16* hct      = (__bf16*)alloc((size_t)1024 * DINNER * 2);

    // ---- weight prep (bf16, transposed to K-contiguous) ----
    patchw_kernel<<<4096, 256, 0, stream>>>(patch_w, WtT);
    for (int dir = 0; dir < 2; dir++)
        for (int i = 0; i < 2; i++) {
            tconv_kernel<<<(256 * 1096 + 255) / 256, 256, 0, stream>>>(
                w_inproj[dir] + (size_t)i * 256 * DPROJ, inprojT + (size_t)(dir * 2 + i) * 1152 * 256, 256, DPROJ);
            tconv_kernel<<<(512 * 256 + 255) / 256, 256, 0, stream>>>(
                w_outproj[dir] + (size_t)i * DINNER * DMODEL, outprojT + (size_t)(dir * 2 + i) * 256 * 512, 512, 256);
        }
    tconv_kernel<<<(512 * 128 + 255) / 256, 256, 0, stream>>>(patch_out_w, poT, 512, 128);
    aux_kernel<<<BSZ, 256, 0, stream>>>(y_aux, aux_w, aux_b, auxb);

    // ---- pre-conv + patch GEMM (split-K 8, atomic into zeroed Cp) ----
    preconv_kernel<<<BSZ * (TPREF / 16), 256, 0, stream>>>(x_prefix, pre_conv_w, pre_conv_b, A_patch);
    hipMemsetAsync(Cp, 0, (size_t)3072 * 256 * 4, stream);
    gemm_mfma<<<dim3(2, 24, 8), 256, 0, stream>>>(A_patch, WtT, Cp, nullptr, 256, 4096, 256, 2);
    assemble_kernel<<<(BSZ * NTOK * DMODEL) / 256, 256, 0, stream>>>(Cp, patch_b, mask_token, auxb, h_f, h_b);

    for (int dir = 0; dir < 2; dir++) {
        float* h = (dir == 0) ? h_f : h_b;
        int T = (dir == 0) ? NTOK : TBWD;
        int M = BSZ * T;
        for (int i = 0; i < 2; i++) {
            const __bf16* ipT = inprojT + (size_t)(dir * 2 + i) * 1152 * 256;
            const __bf16* opT = outprojT + (size_t)(dir * 2 + i) * 256 * 512;
            rmsnorm256_kernel<<<M, 64, 0, stream>>>(h, w_norm[dir] + i * 256, u);
            gemm_mfma<<<dim3(9, M / 128, 1), 256, 0, stream>>>(u, ipT, zx, nullptr, DPROJ, 256, DPROJ, 0);
            dt_kernel<<<(M * NHEADS + 255) / 256, 256, 0, stream>>>(zx, w_dtb[dir] + i * 8, dtb, M);
            dwconv_kernel<<<(M * CONVDIM + 255) / 256, 256, 0, stream>>>(
                zx, w_convw[dir] + i * CONVDIM * 4, w_convb[dir] + i * CONVDIM, xbc, T, M);
            scan_kernel<<<dim3(NHEADS, BSZ), 256, 0, stream>>>(xbc, dtb, w_alog[dir] + i * 8,
                                                               w_D[dir] + i * 8, ysD, T);
            gatednorm_kernel<<<M, 64, 0, stream>>>(ysD, zx, w_gnorm[dir] + i * DINNER, y2);
            // outproj accumulates into residual h via atomics (split-K 2)
            gemm_mfma<<<dim3(2, M / 128, 2), 256, 0, stream>>>(y2, opT, h, nullptr, 256, 512, 256, 2);
        }
    }

    hcat_kernel<<<(BSZ * TBWD * DINNER) / 256, 256, 0, stream>>>(h_f, h_b, hct);
    biasout_kernel<<<(BSZ * TBWD * 128) / 256, 256, 0, stream>>>(patch_out_b, (float*)d_out);
    // final patch_out GEMM, split-K 4, atomic into bias-initialized d_out
    gemm_mfma<<<dim3(1, 8, 4), 256, 0, stream>>>(hct, poT, (float*)d_out, nullptr, 128, 512, 128, 2);
}

// Round 3
// 554.038 us; speedup vs baseline: 2.8422x; 1.7824x over previous
//
#include <hip/hip_runtime.h>
#include <hip/hip_bf16.h>
#include <math.h>

// ---------------- constants ----------------
#define BSZ      8
#define TPREF    6144
#define CIN      8
#define DMODEL   256
#define DINNER   512
#define DSTATE   32
#define NHEADS   8
#define HEADDIM  64
#define CONVDIM  576
#define DPROJ    1096
#define NTOK     512
#define NVIS     384     // unmasked tokens
#define TBWD     128     // bwd truncation (tokens 384..511 reversed)

typedef float f32x4 __attribute__((ext_vector_type(4)));
typedef __bf16 bf16x8 __attribute__((ext_vector_type(8)));

__device__ __forceinline__ float silu_f(float x) { return x / (1.f + expf(-x)); }

#define ASYNC16(gp, lp) \
    __builtin_amdgcn_global_load_lds((const __attribute__((address_space(1))) void*)(gp), \
                                     (__attribute__((address_space(3))) void*)(lp), 16, 0, 0)

// ---------------- bf16 MFMA GEMM (NT layout: C[m,n] = sum_k A[m,k]*Bt[n,k]) ----------------
__global__ __launch_bounds__(256) void gemm_mfma(
    const __bf16* __restrict__ A, const __bf16* __restrict__ Bt,
    float* __restrict__ C, const float* __restrict__ bias,
    int N, int K, int ldc, int flags) {
    __shared__ char sm[16384];                  // A tile 8KB | B tile 8KB
    int tid = threadIdx.x;
    int m0 = blockIdx.y * 128, n0 = blockIdx.x * 128;
    int klen = K / gridDim.z;
    int kbeg = blockIdx.z * klen;
    int w = tid >> 6, l = tid & 63;
    int wm = w >> 1, wn = w & 1;
    int lm = l & 15, q = l >> 4;

    f32x4 acc[4][4];
    #pragma unroll
    for (int i = 0; i < 4; i++)
        #pragma unroll
        for (int j = 0; j < 4; j++) acc[i][j] = (f32x4)0.f;

    for (int k0 = 0; k0 < klen; k0 += 32) {
        int kb = kbeg + k0;
        #pragma unroll
        for (int i = 0; i < 2; i++) {
            int s = i * 256 + tid;
            ASYNC16(A + (size_t)(m0 + (s >> 2)) * K + kb + (s & 3) * 8, sm + s * 16);
        }
        #pragma unroll
        for (int i = 0; i < 2; i++) {
            int s = i * 256 + tid;
            ASYNC16(Bt + (size_t)(n0 + (s >> 2)) * K + kb + (s & 3) * 8, sm + 8192 + s * 16);
        }
        __syncthreads();
        bf16x8 af[4], bfr[4];
        #pragma unroll
        for (int mf = 0; mf < 4; mf++)
            af[mf] = *(const bf16x8*)(sm + (wm * 64 + mf * 16 + lm) * 64 + q * 16);
        #pragma unroll
        for (int nf = 0; nf < 4; nf++)
            bfr[nf] = *(const bf16x8*)(sm + 8192 + (wn * 64 + nf * 16 + lm) * 64 + q * 16);
        #pragma unroll
        for (int mf = 0; mf < 4; mf++)
            #pragma unroll
            for (int nf = 0; nf < 4; nf++)
                acc[mf][nf] = __builtin_amdgcn_mfma_f32_16x16x32_bf16(af[mf], bfr[nf], acc[mf][nf], 0, 0, 0);
        __syncthreads();
    }

    #pragma unroll
    for (int mf = 0; mf < 4; mf++) {
        int mbase = m0 + wm * 64 + mf * 16 + q * 4;
        #pragma unroll
        for (int nf = 0; nf < 4; nf++) {
            int n = n0 + wn * 64 + nf * 16 + lm;
            if (n < N) {
                #pragma unroll
                for (int r = 0; r < 4; r++) {
                    float v = acc[mf][nf][r];
                    size_t ci = (size_t)(mbase + r) * ldc + n;
                    if (flags & 2) atomicAdd(C + ci, v);
                    else C[ci] = v + (bias ? bias[n] : 0.f);
                }
            }
        }
    }
}

// ---------------- prep / conversion kernels ----------------

__global__ void tconv_kernel(const float* __restrict__ src, __bf16* __restrict__ dst, int K, int N) {
    int idx = blockIdx.x * 256 + threadIdx.x;
    if (idx >= K * N) return;
    int k = idx / N, n = idx % N;
    dst[(size_t)n * K + k] = (__bf16)src[idx];
}

__global__ void patchw_kernel(const float* __restrict__ pw, __bf16* __restrict__ dst) {
    int idx = blockIdx.x * 256 + threadIdx.x;           // 1048576
    if (idx >= 256 * 256 * 16) return;
    int k = idx & 15, c = (idx >> 4) & 255, o = idx >> 12;
    dst[(size_t)o * 4096 + k * 256 + c] = (__bf16)pw[idx];
}

__global__ void aux_kernel(const float* __restrict__ y_aux, const float* __restrict__ aux_w,
                           const float* __restrict__ aux_b, float* __restrict__ out) {
    int b = blockIdx.x, o = threadIdx.x;
    float acc = aux_b[o];
    #pragma unroll
    for (int i = 0; i < 16; i++) acc += y_aux[b * 16 + i] * aux_w[i * 256 + o];
    out[b * 256 + o] = silu_f(acc);
}

__global__ void preconv_kernel(const float* __restrict__ xp, const float* __restrict__ w,
                               const float* __restrict__ bias, __bf16* __restrict__ out) {
    int blk = blockIdx.x;                       // B * 384
    int b  = blk / (TPREF / 16);
    int t0 = (blk % (TPREF / 16)) * 16;
    int o  = threadIdx.x;                       // 256
    __shared__ float xs[20][CIN];               // t0-2 .. t0+17
    if (o < 160) {
        int k = o / 8, i = o % 8;
        int tt = t0 - 2 + k;
        xs[k][i] = (tt >= 0 && tt < TPREF) ? xp[(b * TPREF + tt) * CIN + i] : 0.f;
    }
    float wreg[40];
    const float* wo = w + o * 40;               // pre_conv_w[o, i, k]
    #pragma unroll
    for (int j = 0; j < 40; j++) wreg[j] = wo[j];
    float bo = bias[o];
    __syncthreads();
    size_t rbase = (size_t)blk * 4096;
    for (int dt_ = 0; dt_ < 16; dt_++) {
        float acc = bo;
        #pragma unroll
        for (int i = 0; i < 8; i++)
            #pragma unroll
            for (int k = 0; k < 5; k++)
                acc += wreg[i * 5 + k] * xs[dt_ + k][i];
        out[rbase + dt_ * 256 + o] = (__bf16)silu_f(acc);
    }
}

__global__ void assemble_kernel(const float* __restrict__ Cp, const float* __restrict__ pb,
                                const float* __restrict__ mtok, const float* __restrict__ aux,
                                float* __restrict__ h_f, float* __restrict__ h_b) {
    int idx = blockIdx.x * 256 + threadIdx.x;   // B*512*256
    if (idx >= BSZ * NTOK * DMODEL) return;
    int o = idx & 255, tok = (idx >> 8) & 511, b = idx >> 17;
    float v = (tok < NVIS) ? (Cp[(b * NVIS + tok) * 256 + o] + pb[o]) : mtok[o];
    v += aux[b * 256 + o];
    h_f[idx] = v;
    if (tok >= NVIS) h_b[(b * TBWD + (NTOK - 1 - tok)) * 256 + o] = v;
}

__global__ void biasout_kernel(const float* __restrict__ pb, float* __restrict__ out) {
    int idx = blockIdx.x * 256 + threadIdx.x;   // 1024*128
    if (idx >= BSZ * TBWD * 128) return;
    out[idx] = pb[idx & 127];
}

// ---------------- mamba block kernels ----------------

__global__ void rmsnorm256_kernel(const float* __restrict__ x, const float* __restrict__ w,
                                  __bf16* __restrict__ out) {
    long row = blockIdx.x;
    int tid = threadIdx.x;  // 64
    const float4* xr = (const float4*)(x + row * 256);
    float4 v = xr[tid];
    float ss = v.x * v.x + v.y * v.y + v.z * v.z + v.w * v.w;
    #pragma unroll
    for (int off = 32; off >= 1; off >>= 1) ss += __shfl_xor(ss, off);
    float rs = rsqrtf(ss * (1.f / 256.f) + 1e-5f);
    float4 wv = ((const float4*)w)[tid];
    __bf16* o = out + row * 256 + tid * 4;
    o[0] = (__bf16)(v.x * rs * wv.x);
    o[1] = (__bf16)(v.y * rs * wv.y);
    o[2] = (__bf16)(v.z * rs * wv.z);
    o[3] = (__bf16)(v.w * rs * wv.w);
}

// dt = softplus(zx[...,1088+h] + dtbias[h])  -> dtT[(b*8+h)*T + t]
__global__ void dt_kernel(const float* __restrict__ zx, const float* __restrict__ dtbias,
                          float* __restrict__ dtT, int T, int M) {
    int idx = blockIdx.x * 256 + threadIdx.x;
    if (idx >= M * NHEADS) return;
    int h = idx & 7, row = idx >> 3;
    int t = row % T, b = row / T;
    float x = zx[(long)row * DPROJ + 1088 + h] + dtbias[h];
    float sp = (x > 20.f) ? x : log1pf(expf(x));
    dtT[(size_t)(b * 8 + h) * T + t] = sp;
}

// causal depthwise conv (k=4) + bias + silu; writes scan layouts:
//   Xt bf16 [bh][p(64)][T], BC bf16 [b*T+t][64]
__global__ void dwconv_kernel(const float* __restrict__ zx, const float* __restrict__ cw,
                              const float* __restrict__ cb, __bf16* __restrict__ Xt,
                              __bf16* __restrict__ BC, int T, int M) {
    int idx = blockIdx.x * 256 + threadIdx.x;
    if (idx >= M * CONVDIM) return;
    int c = idx % CONVDIM;
    int row = idx / CONVDIM;
    int t = row % T, b = row / T;
    const float* base = zx + (long)row * DPROJ + DINNER + c;
    float acc = cb[c];
    #pragma unroll
    for (int k = 0; k < 4; k++) {
        int tt = t - 3 + k;
        if (tt >= 0) acc += cw[c * 4 + k] * base[(long)(k - 3) * DPROJ];
    }
    float v = silu_f(acc);
    if (c < DINNER) {
        int h = c >> 6, p = c & 63;
        Xt[(size_t)((b * 8 + h) * 64 + p) * T + t] = (__bf16)v;
    } else {
        BC[(size_t)row * 64 + (c - DINNER)] = (__bf16)v;
    }
}

// ---------------- chunked SSD scan: one wave per (b,h), MFMA intra-chunk ----------------
// Y[i,p] = sum_{j<=i} exp(lc_i-lc_j) dt_j (C_i.B_j) X[j,p] + exp(lc_i) sum_n C[i,n] S[p,n] + D X[i,p]
// S' = exp(lc_63) S + sum_j exp(lc_63-lc_j) dt_j X[j,p] B[j,n]
__global__ __launch_bounds__(64) void scan_chunked(
    const __bf16* __restrict__ Xt, const __bf16* __restrict__ BC,
    const float* __restrict__ dtT, const float* __restrict__ Alog,
    const float* __restrict__ Dp, float* __restrict__ ysD, int T) {
    int hd = blockIdx.x, b = blockIdx.y;
    int bh = b * 8 + hd;
    int lane = threadIdx.x;
    int lm = lane & 15, q = lane >> 4;
    float A = -expf(Alog[hd]);
    float Dh = Dp[hd];

    __shared__ __bf16 Xl[64][72];    // [p][j]
    __shared__ __bf16 BCl[64][72];   // [t][n:64] (B 0..31, C 32..63)
    __shared__ __bf16 Pl[64][72];    // [i][j]
    __shared__ __bf16 Cl[64][40];    // scaled C-hat [i][n:32]
    __shared__ __bf16 Wbl[32][72];   // [n][j] = w_j * B[j][n]
    __shared__ __bf16 Sl[64][40];    // state bf16 [p][n:32]
    __shared__ float lcs[64], dts[64];

    // zero state
    #pragma unroll
    for (int k = 0; k < 16; k++) ((unsigned*)&Sl[lane][0])[k] = 0u;
    f32x4 Sacc[4][2];
    #pragma unroll
    for (int tp = 0; tp < 4; tp++)
        #pragma unroll
        for (int tn = 0; tn < 2; tn++) Sacc[tp][tn] = (f32x4)0.f;

    int NC = T >> 6;
    for (int c = 0; c < NC; c++) {
        int t0 = c * 64;
        // ---- stage: Xt row (p=lane), BC row (t=lane), dt ----
        const uint4* xg = (const uint4*)(Xt + (size_t)(bh * 64 + lane) * T + t0);
        const uint4* bg = (const uint4*)(BC + ((size_t)(b * T + t0 + lane)) * 64);
        uint4 xv[8], bv[8];
        #pragma unroll
        for (int k = 0; k < 8; k++) { xv[k] = xg[k]; bv[k] = bg[k]; }
        float dtv = dtT[(size_t)bh * T + t0 + lane];
        #pragma unroll
        for (int k = 0; k < 8; k++) {
            *(uint4*)&Xl[lane][k * 8] = xv[k];
            *(uint4*)&BCl[lane][k * 8] = bv[k];
        }
        // prefix sum of A*dt over 64 lanes (inclusive)
        float lc = A * dtv;
        #pragma unroll
        for (int off = 1; off < 64; off <<= 1) {
            float o = __shfl_up(lc, off);
            if (lane >= off) lc += o;
        }
        lcs[lane] = lc; dts[lane] = dtv;
        float lc63 = __shfl(lc, 63);
        float wj = expf(lc63 - lc) * dtv;
        float eli = expf(lc);
        float Dc = expf(lc63);
        // C-hat row (lane = i): scale C (cols 32..63) by eli
        #pragma unroll
        for (int k = 0; k < 4; k++) {
            union { uint4 u; __bf16 h[8]; } s; s.u = bv[4 + k];
            union { uint4 u; __bf16 h[8]; } d;
            #pragma unroll
            for (int j = 0; j < 8; j++) d.h[j] = (__bf16)(eli * (float)s.h[j]);
            *(uint4*)&Cl[lane][k * 8] = d.u;
        }
        // Wb transposed column (lane = j): Wbl[n][j] = wj * B[j][n]
        #pragma unroll
        for (int k = 0; k < 4; k++) {
            union { uint4 u; __bf16 h[8]; } s; s.u = bv[k];
            #pragma unroll
            for (int j = 0; j < 8; j++) Wbl[k * 8 + j][lane] = (__bf16)(wj * (float)s.h[j]);
        }
        __syncthreads();

        // ---- G = C @ B^T, apply W mask/decay, write P (bf16) ----
        bf16x8 cfr[4], bfr[4];
        #pragma unroll
        for (int t4 = 0; t4 < 4; t4++) {
            cfr[t4] = *(const bf16x8*)&BCl[t4 * 16 + lm][32 + q * 8];
            bfr[t4] = *(const bf16x8*)&BCl[t4 * 16 + lm][q * 8];
        }
        #pragma unroll
        for (int ti = 0; ti < 4; ti++) {
            float lci[4];
            #pragma unroll
            for (int r = 0; r < 4; r++) lci[r] = lcs[ti * 16 + q * 4 + r];
            #pragma unroll
            for (int tj = 0; tj < 4; tj++) {
                if (tj > ti) {
                    #pragma unroll
                    for (int r = 0; r < 4; r++) Pl[ti * 16 + q * 4 + r][tj * 16 + lm] = (__bf16)0.f;
                    continue;
                }
                f32x4 g = __builtin_amdgcn_mfma_f32_16x16x32_bf16(cfr[ti], bfr[tj], (f32x4)0.f, 0, 0, 0);
                int j = tj * 16 + lm;
                float lcj = lcs[j], dtj = dts[j];
                #pragma unroll
                for (int r = 0; r < 4; r++) {
                    int i = ti * 16 + q * 4 + r;
                    float v = (j <= i) ? g[r] * expf(lci[r] - lcj) * dtj : 0.f;
                    if (j == i) v += Dh;
                    Pl[i][j] = (__bf16)v;
                }
            }
        }
        __syncthreads();

        // ---- Y = Chat @ S^T + P @ X ; and S update ----
        bf16x8 pf0[4], pf1[4], xf0[4], xf1[4], ccf[4], sf[4];
        #pragma unroll
        for (int t4 = 0; t4 < 4; t4++) {
            ccf[t4] = *(const bf16x8*)&Cl[t4 * 16 + lm][q * 8];
            sf[t4]  = *(const bf16x8*)&Sl[t4 * 16 + lm][q * 8];
            pf0[t4] = *(const bf16x8*)&Pl[t4 * 16 + lm][q * 8];
            pf1[t4] = *(const bf16x8*)&Pl[t4 * 16 + lm][32 + q * 8];
            xf0[t4] = *(const bf16x8*)&Xl[t4 * 16 + lm][q * 8];
            xf1[t4] = *(const bf16x8*)&Xl[t4 * 16 + lm][32 + q * 8];
        }
        #pragma unroll
        for (int ti = 0; ti < 4; ti++) {
            #pragma unroll
            for (int tp = 0; tp < 4; tp++) {
                f32x4 y = __builtin_amdgcn_mfma_f32_16x16x32_bf16(ccf[ti], sf[tp], (f32x4)0.f, 0, 0, 0);
                y = __builtin_amdgcn_mfma_f32_16x16x32_bf16(pf0[ti], xf0[tp], y, 0, 0, 0);
                y = __builtin_amdgcn_mfma_f32_16x16x32_bf16(pf1[ti], xf1[tp], y, 0, 0, 0);
                #pragma unroll
                for (int r = 0; r < 4; r++) {
                    int i = ti * 16 + q * 4 + r;
                    ysD[((size_t)(b * T + t0 + i)) * DINNER + hd * 64 + tp * 16 + lm] = y[r];
                }
            }
        }
        // S update: S = Dc*S + X^T @ (w.B)
        bf16x8 wf0[2], wf1[2];
        #pragma unroll
        for (int tn = 0; tn < 2; tn++) {
            wf0[tn] = *(const bf16x8*)&Wbl[tn * 16 + lm][q * 8];
            wf1[tn] = *(const bf16x8*)&Wbl[tn * 16 + lm][32 + q * 8];
        }
        #pragma unroll
        for (int tp = 0; tp < 4; tp++) {
            #pragma unroll
            for (int tn = 0; tn < 2; tn++) {
                f32x4 s = Sacc[tp][tn];
                #pragma unroll
                for (int r = 0; r < 4; r++) s[r] *= Dc;
                s = __builtin_amdgcn_mfma_f32_16x16x32_bf16(xf0[tp], wf0[tn], s, 0, 0, 0);
                s = __builtin_amdgcn_mfma_f32_16x16x32_bf16(xf1[tp], wf1[tn], s, 0, 0, 0);
                Sacc[tp][tn] = s;
            }
        }
        __syncthreads();
        #pragma unroll
        for (int tp = 0; tp < 4; tp++)
            #pragma unroll
            for (int tn = 0; tn < 2; tn++)
                #pragma unroll
                for (int r = 0; r < 4; r++)
                    Sl[tp * 16 + q * 4 + r][tn * 16 + lm] = (__bf16)Sacc[tp][tn][r];
        __syncthreads();
    }
}

// y2 = rmsnorm(ysD * silu(z), gnorm) over 512 dims -> bf16; z = zx[...,:512]
__global__ void gatednorm_kernel(const float* __restrict__ ysD, const float* __restrict__ zx,
                                 const float* __restrict__ gw, __bf16* __restrict__ y2) {
    long row = blockIdx.x;
    int tid = threadIdx.x;  // 64 lanes x 8 elems
    const float* yr = ysD + row * DINNER + tid * 8;
    const float* zr = zx + row * DPROJ + tid * 8;
    float g[8];
    float ss = 0.f;
    #pragma unroll
    for (int j = 0; j < 8; j++) {
        float z = zr[j];
        float gg = yr[j] * silu_f(z);
        g[j] = gg;
        ss += gg * gg;
    }
    #pragma unroll
    for (int off = 32; off >= 1; off >>= 1) ss += __shfl_xor(ss, off);
    float rs = rsqrtf(ss * (1.f / 512.f) + 1e-5f);
    __bf16* o = y2 + row * DINNER + tid * 8;
    const float* gwp = gw + tid * 8;
    #pragma unroll
    for (int j = 0; j < 8; j++) o[j] = (__bf16)(g[j] * rs * gwp[j]);
}

__global__ void hcat_kernel(const float* __restrict__ h_f, const float* __restrict__ h_b,
                            __bf16* __restrict__ hc) {
    int idx = blockIdx.x * 256 + threadIdx.x;   // 8*128*512
    if (idx >= BSZ * TBWD * DINNER) return;
    int c = idx & 511, j = (idx >> 9) & 127, b = idx >> 16;
    float v = (c < 256) ? h_f[(b * NTOK + NVIS + j) * 256 + c]
                        : h_b[(b * TBWD + (TBWD - 1 - j)) * 256 + (c - 256)];
    hc[idx] = (__bf16)v;
}

// ---------------- launch ----------------
extern "C" void kernel_launch(void* const* d_in, const int* in_sizes, int n_in,
                              void* d_out, int out_size, void* d_ws, size_t ws_size,
                              hipStream_t stream) {
    const float* x_prefix    = (const float*)d_in[0];
    const float* y_aux       = (const float*)d_in[1];
    const float* pre_conv_w  = (const float*)d_in[2];
    const float* pre_conv_b  = (const float*)d_in[3];
    const float* patch_w     = (const float*)d_in[4];
    const float* patch_b     = (const float*)d_in[5];
    const float* mask_token  = (const float*)d_in[6];
    const float* aux_w       = (const float*)d_in[7];
    const float* aux_b       = (const float*)d_in[8];
    const float* patch_out_w = (const float*)d_in[9];
    const float* patch_out_b = (const float*)d_in[10];
    const float* w_norm[2]   = {(const float*)d_in[11], (const float*)d_in[20]};
    const float* w_inproj[2] = {(const float*)d_in[12], (const float*)d_in[21]};
    const float* w_convw[2]  = {(const float*)d_in[13], (const float*)d_in[22]};
    const float* w_convb[2]  = {(const float*)d_in[14], (const float*)d_in[23]};
    const float* w_dtb[2]    = {(const float*)d_in[15], (const float*)d_in[24]};
    const float* w_alog[2]   = {(const float*)d_in[16], (const float*)d_in[25]};
    const float* w_D[2]      = {(const float*)d_in[17], (const float*)d_in[26]};
    const float* w_gnorm[2]  = {(const float*)d_in[18], (const float*)d_in[27]};
    const float* w_outproj[2]= {(const float*)d_in[19], (const float*)d_in[28]};

    char* p = (char*)d_ws;
    auto alloc = [&](size_t bytes) { char* r = p; p += (bytes + 255) & ~255ULL; return r; };
    __bf16* A_patch  = (__bf16*)alloc((size_t)3072 * 4096 * 2);
    __bf16* WtT      = (__bf16*)alloc((size_t)256 * 4096 * 2);
    __bf16* inprojT  = (__bf16*)alloc((size_t)4 * 1152 * 256 * 2);
    __bf16* outprojT = (__bf16*)alloc((size_t)4 * 256 * 512 * 2);
    __bf16* poT      = (__bf16*)alloc((size_t)128 * 512 * 2);
    float*  auxb     = (float*)alloc(8 * 256 * 4);
    float*  Cp       = (float*)alloc((size_t)3072 * 256 * 4);
    float*  h_f      = (float*)alloc((size_t)BSZ * NTOK * DMODEL * 4);
    float*  h_b      = (float*)alloc((size_t)BSZ * TBWD * DMODEL * 4);
    __bf16* u        = (__bf16*)alloc((size_t)4096 * 256 * 2);
    float*  zx       = (float*)alloc((size_t)4096 * DPROJ * 4);
    float*  dtT      = (float*)alloc((size_t)64 * NTOK * 4);
    __bf16* XtT      = (__bf16*)alloc((size_t)64 * 64 * NTOK * 2);
    __bf16* BCb      = (__bf16*)alloc((size_t)BSZ * NTOK * 64 * 2);
    float*  ysD      = (float*)alloc((size_t)4096 * DINNER * 4);
    __bf16* y2       = (__bf16*)alloc((size_t)4096 * DINNER * 2);
    __bf16* hct      = (__bf16*)alloc((size_t)1024 * DINNER * 2);

    // ---- weight prep (bf16, transposed to K-contiguous) ----
    patchw_kernel<<<4096, 256, 0, stream>>>(patch_w, WtT);
    for (int dir = 0; dir < 2; dir++)
        for (int i = 0; i < 2; i++) {
            tconv_kernel<<<(256 * 1096 + 255) / 256, 256, 0, stream>>>(
                w_inproj[dir] + (size_t)i * 256 * DPROJ, inprojT + (size_t)(dir * 2 + i) * 1152 * 256, 256, DPROJ);
            tconv_kernel<<<(512 * 256 + 255) / 256, 256, 0, stream>>>(
                w_outproj[dir] + (size_t)i * DINNER * DMODEL, outprojT + (size_t)(dir * 2 + i) * 256 * 512, 512, 256);
        }
    tconv_kernel<<<(512 * 128 + 255) / 256, 256, 0, stream>>>(patch_out_w, poT, 512, 128);
    aux_kernel<<<BSZ, 256, 0, stream>>>(y_aux, aux_w, aux_b, auxb);

    // ---- pre-conv + patch GEMM (split-K 8, atomic into zeroed Cp) ----
    preconv_kernel<<<BSZ * (TPREF / 16), 256, 0, stream>>>(x_prefix, pre_conv_w, pre_conv_b, A_patch);
    hipMemsetAsync(Cp, 0, (size_t)3072 * 256 * 4, stream);
    gemm_mfma<<<dim3(2, 24, 8), 256, 0, stream>>>(A_patch, WtT, Cp, nullptr, 256, 4096, 256, 2);
    assemble_kernel<<<(BSZ * NTOK * DMODEL) / 256, 256, 0, stream>>>(Cp, patch_b, mask_token, auxb, h_f, h_b);

    for (int dir = 0; dir < 2; dir++) {
        float* h = (dir == 0) ? h_f : h_b;
        int T = (dir == 0) ? NTOK : TBWD;
        int M = BSZ * T;
        for (int i = 0; i < 2; i++) {
            const __bf16* ipT = inprojT + (size_t)(dir * 2 + i) * 1152 * 256;
            const __bf16* opT = outprojT + (size_t)(dir * 2 + i) * 256 * 512;
            rmsnorm256_kernel<<<M, 64, 0, stream>>>(h, w_norm[dir] + i * 256, u);
            gemm_mfma<<<dim3(9, M / 128, 1), 256, 0, stream>>>(u, ipT, zx, nullptr, DPROJ, 256, DPROJ, 0);
            dt_kernel<<<(M * NHEADS + 255) / 256, 256, 0, stream>>>(zx, w_dtb[dir] + i * 8, dtT, T, M);
            dwconv_kernel<<<(M * CONVDIM + 255) / 256, 256, 0, stream>>>(
                zx, w_convw[dir] + i * CONVDIM * 4, w_convb[dir] + i * CONVDIM, XtT, BCb, T, M);
            scan_chunked<<<dim3(NHEADS, BSZ), 64, 0, stream>>>(XtT, BCb, dtT, w_alog[dir] + i * 8,
                                                               w_D[dir] + i * 8, ysD, T);
            gatednorm_kernel<<<M, 64, 0, stream>>>(ysD, zx, w_gnorm[dir] + i * DINNER, y2);
            gemm_mfma<<<dim3(2, M / 128, 2), 256, 0, stream>>>(y2, opT, h, nullptr, 256, 512, 256, 2);
        }
    }

    hcat_kernel<<<(BSZ * TBWD * DINNER) / 256, 256, 0, stream>>>(h_f, h_b, hct);
    biasout_kernel<<<(BSZ * TBWD * 128) / 256, 256, 0, stream>>>(patch_out_b, (float*)d_out);
    gemm_mfma<<<dim3(1, 8, 4), 256, 0, stream>>>(hct, poT, (float*)d_out, nullptr, 128, 512, 128, 2);
}

// Round 4
// 519.716 us; speedup vs baseline: 3.0299x; 1.0660x over previous
//
#include <hip/hip_runtime.h>
#include <hip/hip_bf16.h>
#include <math.h>

// ---------------- constants ----------------
#define BSZ      8
#define TPREF    6144
#define CIN      8
#define DMODEL   256
#define DINNER   512
#define DSTATE   32
#define NHEADS   8
#define HEADDIM  64
#define CONVDIM  576
#define DPROJ    1096
#define NTOK     512
#define NVIS     384     // unmasked tokens
#define TBWD     128     // bwd truncation (tokens 384..511 reversed)

typedef float f32x4 __attribute__((ext_vector_type(4)));
typedef __bf16 bf16x8 __attribute__((ext_vector_type(8)));

__device__ __forceinline__ float silu_f(float x) { return x / (1.f + expf(-x)); }

#define ASYNC16(gp, lp) \
    __builtin_amdgcn_global_load_lds((const __attribute__((address_space(1))) void*)(gp), \
                                     (__attribute__((address_space(3))) void*)(lp), 16, 0, 0)

// ---------------- bf16 MFMA GEMM (NT layout: C[m,n] = sum_k A[m,k]*Bt[n,k]) ----------------
// flags: 1 = add bias, 2 = atomicAdd into fp32 C, 4 = silu epilogue + bf16 store
__global__ __launch_bounds__(256) void gemm_mfma(
    const __bf16* __restrict__ A, const __bf16* __restrict__ Bt,
    float* __restrict__ C, const float* __restrict__ bias,
    int N, int K, int ldc, int flags) {
    __shared__ char sm[16384];                  // A tile 8KB | B tile 8KB
    int tid = threadIdx.x;
    int m0 = blockIdx.y * 128, n0 = blockIdx.x * 128;
    int klen = K / gridDim.z;
    int kbeg = blockIdx.z * klen;
    int w = tid >> 6, l = tid & 63;
    int wm = w >> 1, wn = w & 1;
    int lm = l & 15, q = l >> 4;

    f32x4 acc[4][4];
    #pragma unroll
    for (int i = 0; i < 4; i++)
        #pragma unroll
        for (int j = 0; j < 4; j++) acc[i][j] = (f32x4)0.f;

    for (int k0 = 0; k0 < klen; k0 += 32) {
        int kb = kbeg + k0;
        #pragma unroll
        for (int i = 0; i < 2; i++) {
            int s = i * 256 + tid;
            ASYNC16(A + (size_t)(m0 + (s >> 2)) * K + kb + (s & 3) * 8, sm + s * 16);
        }
        #pragma unroll
        for (int i = 0; i < 2; i++) {
            int s = i * 256 + tid;
            ASYNC16(Bt + (size_t)(n0 + (s >> 2)) * K + kb + (s & 3) * 8, sm + 8192 + s * 16);
        }
        __syncthreads();
        bf16x8 af[4], bfr[4];
        #pragma unroll
        for (int mf = 0; mf < 4; mf++)
            af[mf] = *(const bf16x8*)(sm + (wm * 64 + mf * 16 + lm) * 64 + q * 16);
        #pragma unroll
        for (int nf = 0; nf < 4; nf++)
            bfr[nf] = *(const bf16x8*)(sm + 8192 + (wn * 64 + nf * 16 + lm) * 64 + q * 16);
        #pragma unroll
        for (int mf = 0; mf < 4; mf++)
            #pragma unroll
            for (int nf = 0; nf < 4; nf++)
                acc[mf][nf] = __builtin_amdgcn_mfma_f32_16x16x32_bf16(af[mf], bfr[nf], acc[mf][nf], 0, 0, 0);
        __syncthreads();
    }

    #pragma unroll
    for (int mf = 0; mf < 4; mf++) {
        int mbase = m0 + wm * 64 + mf * 16 + q * 4;
        #pragma unroll
        for (int nf = 0; nf < 4; nf++) {
            int n = n0 + wn * 64 + nf * 16 + lm;
            if (n < N) {
                #pragma unroll
                for (int r = 0; r < 4; r++) {
                    float v = acc[mf][nf][r];
                    size_t ci = (size_t)(mbase + r) * ldc + n;
                    if (flags & 4) {
                        v = silu_f(v + bias[n]);
                        ((__bf16*)C)[ci] = (__bf16)v;
                    } else if (flags & 2) {
                        atomicAdd(C + ci, v);
                    } else {
                        C[ci] = v + ((flags & 1) ? bias[n] : 0.f);
                    }
                }
            }
        }
    }
}

// ---------------- prep / conversion kernels ----------------

// im2row for pre-conv: Aim[m=b*6144+t][64] = window x[b][t-2..t+2][0..7] (kk = i*5+k), pad->0
__global__ void im2row_kernel(const float* __restrict__ xp, __bf16* __restrict__ Aim) {
    int m = blockIdx.x * 256 + threadIdx.x;
    if (m >= BSZ * TPREF) return;
    int t = m % TPREF, b = m / TPREF;
    __bf16 d[64];
    #pragma unroll
    for (int k = 0; k < 5; k++) {
        int tt = t - 2 + k;
        bool ok = (tt >= 0) && (tt < TPREF);
        const float* s = xp + ((size_t)b * TPREF + tt) * 8;
        #pragma unroll
        for (int i = 0; i < 8; i++)
            d[i * 5 + k] = ok ? (__bf16)s[i] : (__bf16)0.f;
    }
    #pragma unroll
    for (int j = 40; j < 64; j++) d[j] = (__bf16)0.f;
    uint4* o = (uint4*)(Aim + (size_t)m * 64);
    #pragma unroll
    for (int k = 0; k < 8; k++) o[k] = ((const uint4*)d)[k];
}

// pre_conv_w[o][i][k] -> WpreT[o][64] (kk = i*5+k, pad 0); coalesced writes
__global__ void prew_kernel(const float* __restrict__ w, __bf16* __restrict__ dst) {
    int idx = blockIdx.x * 256 + threadIdx.x;   // 256*64
    if (idx >= 256 * 64) return;
    int o = idx >> 6, kk = idx & 63;
    dst[idx] = (kk < 40) ? (__bf16)w[o * 40 + kk] : (__bf16)0.f;
}

// patch_w [o][c][k16] fp32 -> WtT bf16 [o][k*256+c]; output-indexed (coalesced writes)
__global__ void patchw_kernel(const float* __restrict__ pw, __bf16* __restrict__ dst) {
    int idx = blockIdx.x * 256 + threadIdx.x;           // 1048576
    if (idx >= 256 * 256 * 16) return;
    int kk = idx & 4095, o = idx >> 12;
    int k = kk >> 8, c = kk & 255;
    dst[idx] = (__bf16)pw[(o << 12) + (c << 4) + k];
}

// all inproj/outproj/patch_out transposes in one launch; output-indexed.
// seg 0..3: inprojT[seg][1152][256]; seg 4..7: outprojT[seg-4][256][512]; seg 8: poT[128][512]
__global__ void prep_weights_kernel(const float* __restrict__ ip0, const float* __restrict__ ip1,
                                    const float* __restrict__ op0, const float* __restrict__ op1,
                                    const float* __restrict__ pow_, __bf16* __restrict__ inprojT,
                                    __bf16* __restrict__ outprojT, __bf16* __restrict__ poT) {
    int seg = blockIdx.y;
    int idx = blockIdx.x * 256 + threadIdx.x;
    if (seg < 4) {
        if (idx >= 1152 * 256) return;
        int n = idx >> 8, k = idx & 255;
        const float* src = (seg < 2 ? ip0 : ip1) + (size_t)(seg & 1) * 256 * DPROJ;
        inprojT[(size_t)seg * 1152 * 256 + idx] =
            (n < DPROJ) ? (__bf16)src[(size_t)k * DPROJ + n] : (__bf16)0.f;
    } else if (seg < 8) {
        if (idx >= 256 * 512) return;
        int s = seg - 4;
        int n = idx >> 9, k = idx & 511;
        const float* src = (s < 2 ? op0 : op1) + (size_t)(s & 1) * DINNER * DMODEL;
        outprojT[(size_t)s * 256 * 512 + idx] = (__bf16)src[(size_t)k * DMODEL + n];
    } else {
        if (idx >= 128 * 512) return;
        int n = idx >> 9, k = idx & 511;
        poT[idx] = (__bf16)pow_[(size_t)k * 128 + n];
    }
}

__global__ void aux_kernel(const float* __restrict__ y_aux, const float* __restrict__ aux_w,
                           const float* __restrict__ aux_b, float* __restrict__ out) {
    int b = blockIdx.x, o = threadIdx.x;
    float acc = aux_b[o];
    #pragma unroll
    for (int i = 0; i < 16; i++) acc += y_aux[b * 16 + i] * aux_w[i * 256 + o];
    out[b * 256 + o] = silu_f(acc);
}

__global__ void assemble_kernel(const float* __restrict__ Cp, const float* __restrict__ pb,
                                const float* __restrict__ mtok, const float* __restrict__ aux,
                                float* __restrict__ h_f, float* __restrict__ h_b) {
    int idx = blockIdx.x * 256 + threadIdx.x;   // B*512*256
    if (idx >= BSZ * NTOK * DMODEL) return;
    int o = idx & 255, tok = (idx >> 8) & 511, b = idx >> 17;
    float v = (tok < NVIS) ? (Cp[(b * NVIS + tok) * 256 + o] + pb[o]) : mtok[o];
    v += aux[b * 256 + o];
    h_f[idx] = v;
    if (tok >= NVIS) h_b[(b * TBWD + (NTOK - 1 - tok)) * 256 + o] = v;
}

__global__ void biasout_kernel(const float* __restrict__ pb, float* __restrict__ out) {
    int idx = blockIdx.x * 256 + threadIdx.x;   // 1024*128
    if (idx >= BSZ * TBWD * 128) return;
    out[idx] = pb[idx & 127];
}

// ---------------- mamba block kernels ----------------

__global__ void rmsnorm256_kernel(const float* __restrict__ x, const float* __restrict__ w,
                                  __bf16* __restrict__ out) {
    long row = blockIdx.x;
    int tid = threadIdx.x;  // 64
    const float4* xr = (const float4*)(x + row * 256);
    float4 v = xr[tid];
    float ss = v.x * v.x + v.y * v.y + v.z * v.z + v.w * v.w;
    #pragma unroll
    for (int off = 32; off >= 1; off >>= 1) ss += __shfl_xor(ss, off);
    float rs = rsqrtf(ss * (1.f / 256.f) + 1e-5f);
    float4 wv = ((const float4*)w)[tid];
    __bf16* o = out + row * 256 + tid * 4;
    o[0] = (__bf16)(v.x * rs * wv.x);
    o[1] = (__bf16)(v.y * rs * wv.y);
    o[2] = (__bf16)(v.z * rs * wv.z);
    o[3] = (__bf16)(v.w * rs * wv.w);
}

// dt = softplus(zx[...,1088+h] + dtbias[h])  -> dtT[(b*8+h)*T + t]
__global__ void dt_kernel(const float* __restrict__ zx, const float* __restrict__ dtbias,
                          float* __restrict__ dtT, int T, int M) {
    int idx = blockIdx.x * 256 + threadIdx.x;
    if (idx >= M * NHEADS) return;
    int h = idx & 7, row = idx >> 3;
    int t = row % T, b = row / T;
    float x = zx[(long)row * DPROJ + 1088 + h] + dtbias[h];
    float sp = (x > 20.f) ? x : log1pf(expf(x));
    dtT[(size_t)(b * 8 + h) * T + t] = sp;
}

// causal depthwise conv (k=4) + bias + silu with LDS staging; coalesced outputs.
// grid (9, T/64, B); block 256. cg<8 -> Xt[bh][p][T] (t-contig); cg==8 -> BC[bt][64] (n-contig)
__global__ __launch_bounds__(256) void dwconv2_kernel(
    const float* __restrict__ zx, const float* __restrict__ cw, const float* __restrict__ cb,
    __bf16* __restrict__ Xt, __bf16* __restrict__ BC, int T) {
    int cg = blockIdx.x;
    int t0 = blockIdx.y * 64;
    int b  = blockIdx.z;
    int c0 = cg * 64;
    __shared__ float xs[67][65];
    int lane = threadIdx.x & 63, grp = threadIdx.x >> 6;
    for (int r = grp; r < 67; r += 4) {
        int t = t0 - 3 + r;
        xs[r][lane] = (t >= 0) ? zx[((size_t)(b * T + t)) * DPROJ + DINNER + c0 + lane] : 0.f;
    }
    __syncthreads();
    if (cg < 8) {
        int t = lane;
        #pragma unroll
        for (int ci = grp; ci < 64; ci += 4) {
            int c = c0 + ci;
            float acc = cb[c];
            #pragma unroll
            for (int k = 0; k < 4; k++) acc += cw[c * 4 + k] * xs[t + k][ci];
            Xt[((size_t)((b * 8 + cg) * 64 + ci)) * T + t0 + t] = (__bf16)silu_f(acc);
        }
    } else {
        int c = lane;
        #pragma unroll
        for (int ti = grp; ti < 64; ti += 4) {
            float acc = cb[c0 + c];
            #pragma unroll
            for (int k = 0; k < 4; k++) acc += cw[(c0 + c) * 4 + k] * xs[ti + k][c];
            BC[((size_t)(b * T + t0 + ti)) * 64 + c] = (__bf16)silu_f(acc);
        }
    }
}

// ---------------- chunked SSD scan: one wave per (b,h), MFMA intra-chunk ----------------
__global__ __launch_bounds__(64) void scan_chunked(
    const __bf16* __restrict__ Xt, const __bf16* __restrict__ BC,
    const float* __restrict__ dtT, const float* __restrict__ Alog,
    const float* __restrict__ Dp, float* __restrict__ ysD, int T) {
    int hd = blockIdx.x, b = blockIdx.y;
    int bh = b * 8 + hd;
    int lane = threadIdx.x;
    int lm = lane & 15, q = lane >> 4;
    float A = -expf(Alog[hd]);
    float Dh = Dp[hd];

    __shared__ __bf16 Xl[64][72];    // [p][j]
    __shared__ __bf16 BCl[64][72];   // [t][n:64] (B 0..31, C 32..63)
    __shared__ __bf16 Pl[64][72];    // [i][j]
    __shared__ __bf16 Cl[64][40];    // scaled C-hat [i][n:32]
    __shared__ __bf16 Wbl[32][72];   // [n][j] = w_j * B[j][n]
    __shared__ __bf16 Sl[64][40];    // state bf16 [p][n:32]
    __shared__ float lcs[64], dts[64];

    #pragma unroll
    for (int k = 0; k < 16; k++) ((unsigned*)&Sl[lane][0])[k] = 0u;
    f32x4 Sacc[4][2];
    #pragma unroll
    for (int tp = 0; tp < 4; tp++)
        #pragma unroll
        for (int tn = 0; tn < 2; tn++) Sacc[tp][tn] = (f32x4)0.f;

    int NC = T >> 6;
    for (int c = 0; c < NC; c++) {
        int t0 = c * 64;
        const uint4* xg = (const uint4*)(Xt + (size_t)(bh * 64 + lane) * T + t0);
        const uint4* bg = (const uint4*)(BC + ((size_t)(b * T + t0 + lane)) * 64);
        uint4 xv[8], bv[8];
        #pragma unroll
        for (int k = 0; k < 8; k++) { xv[k] = xg[k]; bv[k] = bg[k]; }
        float dtv = dtT[(size_t)bh * T + t0 + lane];
        #pragma unroll
        for (int k = 0; k < 8; k++) {
            *(uint4*)&Xl[lane][k * 8] = xv[k];
            *(uint4*)&BCl[lane][k * 8] = bv[k];
        }
        float lc = A * dtv;
        #pragma unroll
        for (int off = 1; off < 64; off <<= 1) {
            float o = __shfl_up(lc, off);
            if (lane >= off) lc += o;
        }
        lcs[lane] = lc; dts[lane] = dtv;
        float lc63 = __shfl(lc, 63);
        float wj = expf(lc63 - lc) * dtv;
        float eli = expf(lc);
        float Dc = expf(lc63);
        #pragma unroll
        for (int k = 0; k < 4; k++) {
            union { uint4 u; __bf16 h[8]; } s; s.u = bv[4 + k];
            union { uint4 u; __bf16 h[8]; } d;
            #pragma unroll
            for (int j = 0; j < 8; j++) d.h[j] = (__bf16)(eli * (float)s.h[j]);
            *(uint4*)&Cl[lane][k * 8] = d.u;
        }
        #pragma unroll
        for (int k = 0; k < 4; k++) {
            union { uint4 u; __bf16 h[8]; } s; s.u = bv[k];
            #pragma unroll
            for (int j = 0; j < 8; j++) Wbl[k * 8 + j][lane] = (__bf16)(wj * (float)s.h[j]);
        }
        __syncthreads();

        bf16x8 cfr[4], bfr[4];
        #pragma unroll
        for (int t4 = 0; t4 < 4; t4++) {
            cfr[t4] = *(const bf16x8*)&BCl[t4 * 16 + lm][32 + q * 8];
            bfr[t4] = *(const bf16x8*)&BCl[t4 * 16 + lm][q * 8];
        }
        #pragma unroll
        for (int ti = 0; ti < 4; ti++) {
            float lci[4];
            #pragma unroll
            for (int r = 0; r < 4; r++) lci[r] = lcs[ti * 16 + q * 4 + r];
            #pragma unroll
            for (int tj = 0; tj < 4; tj++) {
                if (tj > ti) {
                    #pragma unroll
                    for (int r = 0; r < 4; r++) Pl[ti * 16 + q * 4 + r][tj * 16 + lm] = (__bf16)0.f;
                    continue;
                }
                f32x4 g = __builtin_amdgcn_mfma_f32_16x16x32_bf16(cfr[ti], bfr[tj], (f32x4)0.f, 0, 0, 0);
                int j = tj * 16 + lm;
                float lcj = lcs[j], dtj = dts[j];
                #pragma unroll
                for (int r = 0; r < 4; r++) {
                    int i = ti * 16 + q * 4 + r;
                    float v = (j <= i) ? g[r] * expf(lci[r] - lcj) * dtj : 0.f;
                    if (j == i) v += Dh;
                    Pl[i][j] = (__bf16)v;
                }
            }
        }
        __syncthreads();

        bf16x8 pf0[4], pf1[4], xf0[4], xf1[4], ccf[4], sf[4];
        #pragma unroll
        for (int t4 = 0; t4 < 4; t4++) {
            ccf[t4] = *(const bf16x8*)&Cl[t4 * 16 + lm][q * 8];
            sf[t4]  = *(const bf16x8*)&Sl[t4 * 16 + lm][q * 8];
            pf0[t4] = *(const bf16x8*)&Pl[t4 * 16 + lm][q * 8];
            pf1[t4] = *(const bf16x8*)&Pl[t4 * 16 + lm][32 + q * 8];
            xf0[t4] = *(const bf16x8*)&Xl[t4 * 16 + lm][q * 8];
            xf1[t4] = *(const bf16x8*)&Xl[t4 * 16 + lm][32 + q * 8];
        }
        #pragma unroll
        for (int ti = 0; ti < 4; ti++) {
            #pragma unroll
            for (int tp = 0; tp < 4; tp++) {
                f32x4 y = __builtin_amdgcn_mfma_f32_16x16x32_bf16(ccf[ti], sf[tp], (f32x4)0.f, 0, 0, 0);
                y = __builtin_amdgcn_mfma_f32_16x16x32_bf16(pf0[ti], xf0[tp], y, 0, 0, 0);
                y = __builtin_amdgcn_mfma_f32_16x16x32_bf16(pf1[ti], xf1[tp], y, 0, 0, 0);
                #pragma unroll
                for (int r = 0; r < 4; r++) {
                    int i = ti * 16 + q * 4 + r;
                    ysD[((size_t)(b * T + t0 + i)) * DINNER + hd * 64 + tp * 16 + lm] = y[r];
                }
            }
        }
        bf16x8 wf0[2], wf1[2];
        #pragma unroll
        for (int tn = 0; tn < 2; tn++) {
            wf0[tn] = *(const bf16x8*)&Wbl[tn * 16 + lm][q * 8];
            wf1[tn] = *(const bf16x8*)&Wbl[tn * 16 + lm][32 + q * 8];
        }
        #pragma unroll
        for (int tp = 0; tp < 4; tp++) {
            #pragma unroll
            for (int tn = 0; tn < 2; tn++) {
                f32x4 s = Sacc[tp][tn];
                #pragma unroll
                for (int r = 0; r < 4; r++) s[r] *= Dc;
                s = __builtin_amdgcn_mfma_f32_16x16x32_bf16(xf0[tp], wf0[tn], s, 0, 0, 0);
                s = __builtin_amdgcn_mfma_f32_16x16x32_bf16(xf1[tp], wf1[tn], s, 0, 0, 0);
                Sacc[tp][tn] = s;
            }
        }
        __syncthreads();
        #pragma unroll
        for (int tp = 0; tp < 4; tp++)
            #pragma unroll
            for (int tn = 0; tn < 2; tn++)
                #pragma unroll
                for (int r = 0; r < 4; r++)
                    Sl[tp * 16 + q * 4 + r][tn * 16 + lm] = (__bf16)Sacc[tp][tn][r];
        __syncthreads();
    }
}

// y2 = rmsnorm(ysD * silu(z), gnorm) over 512 dims -> bf16; z = zx[...,:512]
__global__ void gatednorm_kernel(const float* __restrict__ ysD, const float* __restrict__ zx,
                                 const float* __restrict__ gw, __bf16* __restrict__ y2) {
    long row = blockIdx.x;
    int tid = threadIdx.x;  // 64 lanes x 8 elems
    const float* yr = ysD + row * DINNER + tid * 8;
    const float* zr = zx + row * DPROJ + tid * 8;
    float g[8];
    float ss = 0.f;
    #pragma unroll
    for (int j = 0; j < 8; j++) {
        float z = zr[j];
        float gg = yr[j] * silu_f(z);
        g[j] = gg;
        ss += gg * gg;
    }
    #pragma unroll
    for (int off = 32; off >= 1; off >>= 1) ss += __shfl_xor(ss, off);
    float rs = rsqrtf(ss * (1.f / 512.f) + 1e-5f);
    __bf16* o = y2 + row * DINNER + tid * 8;
    const float* gwp = gw + tid * 8;
    #pragma unroll
    for (int j = 0; j < 8; j++) o[j] = (__bf16)(g[j] * rs * gwp[j]);
}

__global__ void hcat_kernel(const float* __restrict__ h_f, const float* __restrict__ h_b,
                            __bf16* __restrict__ hc) {
    int idx = blockIdx.x * 256 + threadIdx.x;   // 8*128*512
    if (idx >= BSZ * TBWD * DINNER) return;
    int c = idx & 511, j = (idx >> 9) & 127, b = idx >> 16;
    float v = (c < 256) ? h_f[(b * NTOK + NVIS + j) * 256 + c]
                        : h_b[(b * TBWD + (TBWD - 1 - j)) * 256 + (c - 256)];
    hc[idx] = (__bf16)v;
}

// ---------------- launch ----------------
extern "C" void kernel_launch(void* const* d_in, const int* in_sizes, int n_in,
                              void* d_out, int out_size, void* d_ws, size_t ws_size,
                              hipStream_t stream) {
    const float* x_prefix    = (const float*)d_in[0];
    const float* y_aux       = (const float*)d_in[1];
    const float* pre_conv_w  = (const float*)d_in[2];
    const float* pre_conv_b  = (const float*)d_in[3];
    const float* patch_w     = (const float*)d_in[4];
    const float* patch_b     = (const float*)d_in[5];
    const float* mask_token  = (const float*)d_in[6];
    const float* aux_w       = (const float*)d_in[7];
    const float* aux_b       = (const float*)d_in[8];
    const float* patch_out_w = (const float*)d_in[9];
    const float* patch_out_b = (const float*)d_in[10];
    const float* w_norm[2]   = {(const float*)d_in[11], (const float*)d_in[20]};
    const float* w_inproj[2] = {(const float*)d_in[12], (const float*)d_in[21]};
    const float* w_convw[2]  = {(const float*)d_in[13], (const float*)d_in[22]};
    const float* w_convb[2]  = {(const float*)d_in[14], (const float*)d_in[23]};
    const float* w_dtb[2]    = {(const float*)d_in[15], (const float*)d_in[24]};
    const float* w_alog[2]   = {(const float*)d_in[16], (const float*)d_in[25]};
    const float* w_D[2]      = {(const float*)d_in[17], (const float*)d_in[26]};
    const float* w_gnorm[2]  = {(const float*)d_in[18], (const float*)d_in[27]};
    const float* w_outproj[2]= {(const float*)d_in[19], (const float*)d_in[28]};

    char* p = (char*)d_ws;
    auto alloc = [&](size_t bytes) { char* r = p; p += (bytes + 255) & ~255ULL; return r; };
    __bf16* A_patch  = (__bf16*)alloc((size_t)3072 * 4096 * 2);
    __bf16* Aim      = (__bf16*)alloc((size_t)BSZ * TPREF * 64 * 2);
    __bf16* WpreT    = (__bf16*)alloc((size_t)256 * 64 * 2);
    __bf16* WtT      = (__bf16*)alloc((size_t)256 * 4096 * 2);
    __bf16* inprojT  = (__bf16*)alloc((size_t)4 * 1152 * 256 * 2);
    __bf16* outprojT = (__bf16*)alloc((size_t)4 * 256 * 512 * 2);
    __bf16* poT      = (__bf16*)alloc((size_t)128 * 512 * 2);
    float*  auxb     = (float*)alloc(8 * 256 * 4);
    float*  Cp       = (float*)alloc((size_t)3072 * 256 * 4);
    float*  h_f      = (float*)alloc((size_t)BSZ * NTOK * DMODEL * 4);
    float*  h_b      = (float*)alloc((size_t)BSZ * TBWD * DMODEL * 4);
    __bf16* u        = (__bf16*)alloc((size_t)4096 * 256 * 2);
    float*  zx       = (float*)alloc((size_t)4096 * DPROJ * 4);
    float*  dtT      = (float*)alloc((size_t)64 * NTOK * 4);
    __bf16* XtT      = (__bf16*)alloc((size_t)64 * 64 * NTOK * 2);
    __bf16* BCb      = (__bf16*)alloc((size_t)BSZ * NTOK * 64 * 2);
    float*  ysD      = (float*)alloc((size_t)4096 * DINNER * 4);
    __bf16* y2       = (__bf16*)alloc((size_t)4096 * DINNER * 2);
    __bf16* hct      = (__bf16*)alloc((size_t)1024 * DINNER * 2);

    // ---- weight prep ----
    prew_kernel<<<64, 256, 0, stream>>>(pre_conv_w, WpreT);
    patchw_kernel<<<4096, 256, 0, stream>>>(patch_w, WtT);
    prep_weights_kernel<<<dim3(1152, 9), 256, 0, stream>>>(
        w_inproj[0], w_inproj[1], w_outproj[0], w_outproj[1], patch_out_w,
        inprojT, outprojT, poT);
    aux_kernel<<<BSZ, 256, 0, stream>>>(y_aux, aux_w, aux_b, auxb);

    // ---- pre-conv as im2row + MFMA GEMM (silu+bf16 epilogue -> A_patch) ----
    im2row_kernel<<<(BSZ * TPREF) / 256, 256, 0, stream>>>(x_prefix, Aim);
    gemm_mfma<<<dim3(2, (BSZ * TPREF) / 128, 1), 256, 0, stream>>>(
        Aim, WpreT, (float*)A_patch, pre_conv_b, 256, 64, 256, 4);
    // ---- patch GEMM (split-K 8, atomic into zeroed Cp) ----
    hipMemsetAsync(Cp, 0, (size_t)3072 * 256 * 4, stream);
    gemm_mfma<<<dim3(2, 24, 8), 256, 0, stream>>>(A_patch, WtT, Cp, nullptr, 256, 4096, 256, 2);
    assemble_kernel<<<(BSZ * NTOK * DMODEL) / 256, 256, 0, stream>>>(Cp, patch_b, mask_token, auxb, h_f, h_b);

    for (int dir = 0; dir < 2; dir++) {
        float* h = (dir == 0) ? h_f : h_b;
        int T = (dir == 0) ? NTOK : TBWD;
        int M = BSZ * T;
        for (int i = 0; i < 2; i++) {
            const __bf16* ipT = inprojT + (size_t)(dir * 2 + i) * 1152 * 256;
            const __bf16* opT = outprojT + (size_t)(dir * 2 + i) * 256 * 512;
            rmsnorm256_kernel<<<M, 64, 0, stream>>>(h, w_norm[dir] + i * 256, u);
            gemm_mfma<<<dim3(9, M / 128, 1), 256, 0, stream>>>(u, ipT, zx, nullptr, DPROJ, 256, DPROJ, 0);
            dt_kernel<<<(M * NHEADS + 255) / 256, 256, 0, stream>>>(zx, w_dtb[dir] + i * 8, dtT, T, M);
            dwconv2_kernel<<<dim3(9, T / 64, BSZ), 256, 0, stream>>>(
                zx, w_convw[dir] + i * CONVDIM * 4, w_convb[dir] + i * CONVDIM, XtT, BCb, T);
            scan_chunked<<<dim3(NHEADS, BSZ), 64, 0, stream>>>(XtT, BCb, dtT, w_alog[dir] + i * 8,
                                                               w_D[dir] + i * 8, ysD, T);
            gatednorm_kernel<<<M, 64, 0, stream>>>(ysD, zx, w_gnorm[dir] + i * DINNER, y2);
            gemm_mfma<<<dim3(2, M / 128, 2), 256, 0, stream>>>(y2, opT, h, nullptr, 256, 512, 256, 2);
        }
    }

    hcat_kernel<<<(BSZ * TBWD * DINNER) / 256, 256, 0, stream>>>(h_f, h_b, hct);
    biasout_kernel<<<(BSZ * TBWD * 128) / 256, 256, 0, stream>>>(patch_out_b, (float*)d_out);
    gemm_mfma<<<dim3(1, 8, 4), 256, 0, stream>>>(hct, poT, (float*)d_out, nullptr, 128, 512, 128, 2);
}

// Round 5
// 509.624 us; speedup vs baseline: 3.0899x; 1.0198x over previous
//
#include <hip/hip_runtime.h>
#include <hip/hip_bf16.h>
#include <math.h>

// ---------------- constants ----------------
#define BSZ      8
#define TPREF    6144
#define CIN      8
#define DMODEL   256
#define DINNER   512
#define DSTATE   32
#define NHEADS   8
#define HEADDIM  64
#define CONVDIM  576
#define DPROJ    1096
#define NTOK     512
#define NVIS     384     // unmasked tokens
#define TBWD     128     // bwd truncation (tokens 384..511 reversed)

typedef float f32x4 __attribute__((ext_vector_type(4)));
typedef __bf16 bf16x8 __attribute__((ext_vector_type(8)));

__device__ __forceinline__ float silu_f(float x) { return x / (1.f + expf(-x)); }

#define ASYNC16(gp, lp) \
    __builtin_amdgcn_global_load_lds((const __attribute__((address_space(1))) void*)(gp), \
                                     (__attribute__((address_space(3))) void*)(lp), 16, 0, 0)

// ---------------- bf16 MFMA GEMM (NT layout: C[m,n] = sum_k A[m,k]*Bt[n,k]) ----------------
// flags: 1 = add bias, 2 = atomicAdd into fp32 C, 4 = silu epilogue + bf16 store
__global__ __launch_bounds__(256) void gemm_mfma(
    const __bf16* __restrict__ A, const __bf16* __restrict__ Bt,
    float* __restrict__ C, const float* __restrict__ bias,
    int N, int K, int ldc, int flags) {
    __shared__ char sm[16384];                  // A tile 8KB | B tile 8KB
    int tid = threadIdx.x;
    int m0 = blockIdx.y * 128, n0 = blockIdx.x * 128;
    int klen = K / gridDim.z;
    int kbeg = blockIdx.z * klen;
    int w = tid >> 6, l = tid & 63;
    int wm = w >> 1, wn = w & 1;
    int lm = l & 15, q = l >> 4;

    f32x4 acc[4][4];
    #pragma unroll
    for (int i = 0; i < 4; i++)
        #pragma unroll
        for (int j = 0; j < 4; j++) acc[i][j] = (f32x4)0.f;

    for (int k0 = 0; k0 < klen; k0 += 32) {
        int kb = kbeg + k0;
        #pragma unroll
        for (int i = 0; i < 2; i++) {
            int s = i * 256 + tid;
            ASYNC16(A + (size_t)(m0 + (s >> 2)) * K + kb + (s & 3) * 8, sm + s * 16);
        }
        #pragma unroll
        for (int i = 0; i < 2; i++) {
            int s = i * 256 + tid;
            ASYNC16(Bt + (size_t)(n0 + (s >> 2)) * K + kb + (s & 3) * 8, sm + 8192 + s * 16);
        }
        __syncthreads();
        bf16x8 af[4], bfr[4];
        #pragma unroll
        for (int mf = 0; mf < 4; mf++)
            af[mf] = *(const bf16x8*)(sm + (wm * 64 + mf * 16 + lm) * 64 + q * 16);
        #pragma unroll
        for (int nf = 0; nf < 4; nf++)
            bfr[nf] = *(const bf16x8*)(sm + 8192 + (wn * 64 + nf * 16 + lm) * 64 + q * 16);
        #pragma unroll
        for (int mf = 0; mf < 4; mf++)
            #pragma unroll
            for (int nf = 0; nf < 4; nf++)
                acc[mf][nf] = __builtin_amdgcn_mfma_f32_16x16x32_bf16(af[mf], bfr[nf], acc[mf][nf], 0, 0, 0);
        __syncthreads();
    }

    #pragma unroll
    for (int mf = 0; mf < 4; mf++) {
        int mbase = m0 + wm * 64 + mf * 16 + q * 4;
        #pragma unroll
        for (int nf = 0; nf < 4; nf++) {
            int n = n0 + wn * 64 + nf * 16 + lm;
            if (n < N) {
                #pragma unroll
                for (int r = 0; r < 4; r++) {
                    float v = acc[mf][nf][r];
                    size_t ci = (size_t)(mbase + r) * ldc + n;
                    if (flags & 4) {
                        v = silu_f(v + bias[n]);
                        ((__bf16*)C)[ci] = (__bf16)v;
                    } else if (flags & 2) {
                        atomicAdd(C + ci, v);
                    } else {
                        C[ci] = v + ((flags & 1) ? bias[n] : 0.f);
                    }
                }
            }
        }
    }
}

// ---------------- prep / conversion kernels ----------------

// im2row for pre-conv: Aim[m=b*6144+t][64] = window x[b][t-2..t+2][0..7] (kk = i*5+k), pad->0
__global__ void im2row_kernel(const float* __restrict__ xp, __bf16* __restrict__ Aim) {
    int m = blockIdx.x * 256 + threadIdx.x;
    if (m >= BSZ * TPREF) return;
    int t = m % TPREF, b = m / TPREF;
    __bf16 d[64];
    #pragma unroll
    for (int k = 0; k < 5; k++) {
        int tt = t - 2 + k;
        bool ok = (tt >= 0) && (tt < TPREF);
        const float* s = xp + ((size_t)b * TPREF + tt) * 8;
        #pragma unroll
        for (int i = 0; i < 8; i++)
            d[i * 5 + k] = ok ? (__bf16)s[i] : (__bf16)0.f;
    }
    #pragma unroll
    for (int j = 40; j < 64; j++) d[j] = (__bf16)0.f;
    uint4* o = (uint4*)(Aim + (size_t)m * 64);
    #pragma unroll
    for (int k = 0; k < 8; k++) o[k] = ((const uint4*)d)[k];
}

// pre_conv_w[o][i][k] -> WpreT[o][64] (kk = i*5+k, pad 0); coalesced writes
__global__ void prew_kernel(const float* __restrict__ w, __bf16* __restrict__ dst) {
    int idx = blockIdx.x * 256 + threadIdx.x;   // 256*64
    if (idx >= 256 * 64) return;
    int o = idx >> 6, kk = idx & 63;
    dst[idx] = (kk < 40) ? (__bf16)w[o * 40 + kk] : (__bf16)0.f;
}

// patch_w [o][c][k16] fp32 -> WtT bf16 [o][k*256+c]; output-indexed (coalesced writes)
__global__ void patchw_kernel(const float* __restrict__ pw, __bf16* __restrict__ dst) {
    int idx = blockIdx.x * 256 + threadIdx.x;           // 1048576
    if (idx >= 256 * 256 * 16) return;
    int kk = idx & 4095, o = idx >> 12;
    int k = kk >> 8, c = kk & 255;
    dst[idx] = (__bf16)pw[(o << 12) + (c << 4) + k];
}

// all inproj/outproj/patch_out transposes in one launch; output-indexed.
__global__ void prep_weights_kernel(const float* __restrict__ ip0, const float* __restrict__ ip1,
                                    const float* __restrict__ op0, const float* __restrict__ op1,
                                    const float* __restrict__ pow_, __bf16* __restrict__ inprojT,
                                    __bf16* __restrict__ outprojT, __bf16* __restrict__ poT) {
    int seg = blockIdx.y;
    int idx = blockIdx.x * 256 + threadIdx.x;
    if (seg < 4) {
        if (idx >= 1152 * 256) return;
        int n = idx >> 8, k = idx & 255;
        const float* src = (seg < 2 ? ip0 : ip1) + (size_t)(seg & 1) * 256 * DPROJ;
        inprojT[(size_t)seg * 1152 * 256 + idx] =
            (n < DPROJ) ? (__bf16)src[(size_t)k * DPROJ + n] : (__bf16)0.f;
    } else if (seg < 8) {
        if (idx >= 256 * 512) return;
        int s = seg - 4;
        int n = idx >> 9, k = idx & 511;
        const float* src = (s < 2 ? op0 : op1) + (size_t)(s & 1) * DINNER * DMODEL;
        outprojT[(size_t)s * 256 * 512 + idx] = (__bf16)src[(size_t)k * DMODEL + n];
    } else {
        if (idx >= 128 * 512) return;
        int n = idx >> 9, k = idx & 511;
        poT[idx] = (__bf16)pow_[(size_t)k * 128 + n];
    }
}

__global__ void aux_kernel(const float* __restrict__ y_aux, const float* __restrict__ aux_w,
                           const float* __restrict__ aux_b, float* __restrict__ out) {
    int b = blockIdx.x, o = threadIdx.x;
    float acc = aux_b[o];
    #pragma unroll
    for (int i = 0; i < 16; i++) acc += y_aux[b * 16 + i] * aux_w[i * 256 + o];
    out[b * 256 + o] = silu_f(acc);
}

__global__ void assemble_kernel(const float* __restrict__ Cp, const float* __restrict__ pb,
                                const float* __restrict__ mtok, const float* __restrict__ aux,
                                float* __restrict__ h_f, float* __restrict__ h_b) {
    int idx = blockIdx.x * 256 + threadIdx.x;   // B*512*256
    if (idx >= BSZ * NTOK * DMODEL) return;
    int o = idx & 255, tok = (idx >> 8) & 511, b = idx >> 17;
    float v = (tok < NVIS) ? (Cp[(b * NVIS + tok) * 256 + o] + pb[o]) : mtok[o];
    v += aux[b * 256 + o];
    h_f[idx] = v;
    if (tok >= NVIS) h_b[(b * TBWD + (NTOK - 1 - tok)) * 256 + o] = v;
}

__global__ void biasout_kernel(const float* __restrict__ pb, float* __restrict__ out) {
    int idx = blockIdx.x * 256 + threadIdx.x;   // 1024*128
    if (idx >= BSZ * TBWD * 128) return;
    out[idx] = pb[idx & 127];
}

// ---------------- mamba block kernels ----------------

__global__ void rmsnorm256_kernel(const float* __restrict__ x, const float* __restrict__ w,
                                  __bf16* __restrict__ out) {
    long row = blockIdx.x;
    int tid = threadIdx.x;  // 64
    const float4* xr = (const float4*)(x + row * 256);
    float4 v = xr[tid];
    float ss = v.x * v.x + v.y * v.y + v.z * v.z + v.w * v.w;
    #pragma unroll
    for (int off = 32; off >= 1; off >>= 1) ss += __shfl_xor(ss, off);
    float rs = rsqrtf(ss * (1.f / 256.f) + 1e-5f);
    float4 wv = ((const float4*)w)[tid];
    __bf16* o = out + row * 256 + tid * 4;
    o[0] = (__bf16)(v.x * rs * wv.x);
    o[1] = (__bf16)(v.y * rs * wv.y);
    o[2] = (__bf16)(v.z * rs * wv.z);
    o[3] = (__bf16)(v.w * rs * wv.w);
}

// dt = softplus(zx[...,1088+h] + dtbias[h])  -> dtT[(b*8+h)*T + t]
__global__ void dt_kernel(const float* __restrict__ zx, const float* __restrict__ dtbias,
                          float* __restrict__ dtT, int T, int M) {
    int idx = blockIdx.x * 256 + threadIdx.x;
    if (idx >= M * NHEADS) return;
    int h = idx & 7, row = idx >> 3;
    int t = row % T, b = row / T;
    float x = zx[(long)row * DPROJ + 1088 + h] + dtbias[h];
    float sp = (x > 20.f) ? x : log1pf(expf(x));
    dtT[(size_t)(b * 8 + h) * T + t] = sp;
}

// causal depthwise conv (k=4) + bias + silu with LDS staging; coalesced outputs.
__global__ __launch_bounds__(256) void dwconv2_kernel(
    const float* __restrict__ zx, const float* __restrict__ cw, const float* __restrict__ cb,
    __bf16* __restrict__ Xt, __bf16* __restrict__ BC, int T) {
    int cg = blockIdx.x;
    int t0 = blockIdx.y * 64;
    int b  = blockIdx.z;
    int c0 = cg * 64;
    __shared__ float xs[67][65];
    int lane = threadIdx.x & 63, grp = threadIdx.x >> 6;
    for (int r = grp; r < 67; r += 4) {
        int t = t0 - 3 + r;
        xs[r][lane] = (t >= 0) ? zx[((size_t)(b * T + t)) * DPROJ + DINNER + c0 + lane] : 0.f;
    }
    __syncthreads();
    if (cg < 8) {
        int t = lane;
        #pragma unroll
        for (int ci = grp; ci < 64; ci += 4) {
            int c = c0 + ci;
            float acc = cb[c];
            #pragma unroll
            for (int k = 0; k < 4; k++) acc += cw[c * 4 + k] * xs[t + k][ci];
            Xt[((size_t)((b * 8 + cg) * 64 + ci)) * T + t0 + t] = (__bf16)silu_f(acc);
        }
    } else {
        int c = lane;
        #pragma unroll
        for (int ti = grp; ti < 64; ti += 4) {
            float acc = cb[c0 + c];
            #pragma unroll
            for (int k = 0; k < 4; k++) acc += cw[(c0 + c) * 4 + k] * xs[ti + k][c];
            BC[((size_t)(b * T + t0 + ti)) * 64 + c] = (__bf16)silu_f(acc);
        }
    }
}

// ---------------- 3-phase chunked SSD scan ----------------
// Phase A: per (chunk, head, batch) — intra-chunk Y = P@X (+D), dS, Chat, Dc. Fully parallel.
__global__ __launch_bounds__(64) void scan_local(
    const __bf16* __restrict__ Xt, const __bf16* __restrict__ BC,
    const float* __restrict__ dtT, const float* __restrict__ Alog,
    const float* __restrict__ Dp, float* __restrict__ ysD,
    __bf16* __restrict__ Chat, float* __restrict__ dS, float* __restrict__ Dcs, int T) {
    int c = blockIdx.x, hd = blockIdx.y, b = blockIdx.z;
    int bh = b * 8 + hd;
    int NC = T >> 6;
    int t0 = c * 64;
    int lane = threadIdx.x;
    int lm = lane & 15, q = lane >> 4;
    float A = -expf(Alog[hd]);
    float Dh = Dp[hd];

    __shared__ __bf16 Xl[64][72];    // [p][j]
    __shared__ __bf16 BCl[64][72];   // [t][n:64] (B 0..31, C 32..63)
    __shared__ __bf16 Pl[64][72];    // [i][j]
    __shared__ __bf16 Wbl[32][72];   // [n][j] = w_j * B[j][n]
    __shared__ float lcs[64], dts[64];

    const uint4* xg = (const uint4*)(Xt + (size_t)(bh * 64 + lane) * T + t0);
    const uint4* bg = (const uint4*)(BC + ((size_t)(b * T + t0 + lane)) * 64);
    uint4 xv[8], bv[8];
    #pragma unroll
    for (int k = 0; k < 8; k++) { xv[k] = xg[k]; bv[k] = bg[k]; }
    float dtv = dtT[(size_t)bh * T + t0 + lane];
    #pragma unroll
    for (int k = 0; k < 8; k++) {
        *(uint4*)&Xl[lane][k * 8] = xv[k];
        *(uint4*)&BCl[lane][k * 8] = bv[k];
    }
    // inclusive prefix of A*dt
    float lc = A * dtv;
    #pragma unroll
    for (int off = 1; off < 64; off <<= 1) {
        float o = __shfl_up(lc, off);
        if (lane >= off) lc += o;
    }
    lcs[lane] = lc; dts[lane] = dtv;
    float lc63 = __shfl(lc, 63);
    float wj = expf(lc63 - lc) * dtv;
    float eli = expf(lc);
    float Dc = expf(lc63);
    if (lane == 0) Dcs[bh * NC + c] = Dc;
    // Chat row (lane = i): eli * C, direct to global (row = 64B)
    {
        __bf16* co = Chat + ((size_t)(bh * NC + c) * 64 + lane) * 32;
        #pragma unroll
        for (int k = 0; k < 4; k++) {
            union { uint4 u; __bf16 h[8]; } s; s.u = bv[4 + k];
            union { uint4 u; __bf16 h[8]; } d;
            #pragma unroll
            for (int j = 0; j < 8; j++) d.h[j] = (__bf16)(eli * (float)s.h[j]);
            *(uint4*)(co + k * 8) = d.u;
        }
    }
    // Wbl[n][j] = wj * B[j][n]
    #pragma unroll
    for (int k = 0; k < 4; k++) {
        union { uint4 u; __bf16 h[8]; } s; s.u = bv[k];
        #pragma unroll
        for (int j = 0; j < 8; j++) Wbl[k * 8 + j][lane] = (__bf16)(wj * (float)s.h[j]);
    }
    __syncthreads();

    // G = C @ B^T -> masked/decayed P (+D diag)
    bf16x8 cfr[4], bfr[4];
    #pragma unroll
    for (int t4 = 0; t4 < 4; t4++) {
        cfr[t4] = *(const bf16x8*)&BCl[t4 * 16 + lm][32 + q * 8];
        bfr[t4] = *(const bf16x8*)&BCl[t4 * 16 + lm][q * 8];
    }
    #pragma unroll
    for (int ti = 0; ti < 4; ti++) {
        float lci[4];
        #pragma unroll
        for (int r = 0; r < 4; r++) lci[r] = lcs[ti * 16 + q * 4 + r];
        #pragma unroll
        for (int tj = 0; tj < 4; tj++) {
            if (tj > ti) {
                #pragma unroll
                for (int r = 0; r < 4; r++) Pl[ti * 16 + q * 4 + r][tj * 16 + lm] = (__bf16)0.f;
                continue;
            }
            f32x4 g = __builtin_amdgcn_mfma_f32_16x16x32_bf16(cfr[ti], bfr[tj], (f32x4)0.f, 0, 0, 0);
            int j = tj * 16 + lm;
            float lcj = lcs[j], dtj = dts[j];
            #pragma unroll
            for (int r = 0; r < 4; r++) {
                int i = ti * 16 + q * 4 + r;
                float v = (j <= i) ? g[r] * expf(lci[r] - lcj) * dtj : 0.f;
                if (j == i) v += Dh;
                Pl[i][j] = (__bf16)v;
            }
        }
    }
    __syncthreads();

    bf16x8 pf0[4], pf1[4], xf0[4], xf1[4];
    #pragma unroll
    for (int t4 = 0; t4 < 4; t4++) {
        pf0[t4] = *(const bf16x8*)&Pl[t4 * 16 + lm][q * 8];
        pf1[t4] = *(const bf16x8*)&Pl[t4 * 16 + lm][32 + q * 8];
        xf0[t4] = *(const bf16x8*)&Xl[t4 * 16 + lm][q * 8];
        xf1[t4] = *(const bf16x8*)&Xl[t4 * 16 + lm][32 + q * 8];
    }
    // Y_local = P @ X  (plain store; phase C adds cross-chunk term for c>0)
    #pragma unroll
    for (int ti = 0; ti < 4; ti++) {
        #pragma unroll
        for (int tp = 0; tp < 4; tp++) {
            f32x4 y = __builtin_amdgcn_mfma_f32_16x16x32_bf16(pf0[ti], xf0[tp], (f32x4)0.f, 0, 0, 0);
            y = __builtin_amdgcn_mfma_f32_16x16x32_bf16(pf1[ti], xf1[tp], y, 0, 0, 0);
            #pragma unroll
            for (int r = 0; r < 4; r++) {
                int i = ti * 16 + q * 4 + r;
                ysD[((size_t)(b * T + t0 + i)) * DINNER + hd * 64 + tp * 16 + lm] = y[r];
            }
        }
    }
    // dS = X^T @ (w.B), fp32 out
    bf16x8 wf0[2], wf1[2];
    #pragma unroll
    for (int tn = 0; tn < 2; tn++) {
        wf0[tn] = *(const bf16x8*)&Wbl[tn * 16 + lm][q * 8];
        wf1[tn] = *(const bf16x8*)&Wbl[tn * 16 + lm][32 + q * 8];
    }
    float* dso = dS + (size_t)(bh * NC + c) * 2048;
    #pragma unroll
    for (int tp = 0; tp < 4; tp++) {
        #pragma unroll
        for (int tn = 0; tn < 2; tn++) {
            f32x4 s = __builtin_amdgcn_mfma_f32_16x16x32_bf16(xf0[tp], wf0[tn], (f32x4)0.f, 0, 0, 0);
            s = __builtin_amdgcn_mfma_f32_16x16x32_bf16(xf1[tp], wf1[tn], s, 0, 0, 0);
            #pragma unroll
            for (int r = 0; r < 4; r++) {
                int pp = tp * 16 + q * 4 + r, nn = tn * 16 + lm;
                dso[pp * 32 + nn] = s[r];
            }
        }
    }
}

// Phase B: sequential state recurrence per bh (tiny). Sprev[c] = S before chunk c (bf16).
__global__ __launch_bounds__(256) void scan_combine(
    const float* __restrict__ dS, const float* __restrict__ Dcs,
    __bf16* __restrict__ Sprev, int NC) {
    int bh = blockIdx.x;
    int tid = threadIdx.x;          // 256 threads x 8 elems = 2048
    float S[8];
    #pragma unroll
    for (int j = 0; j < 8; j++) S[j] = 0.f;
    for (int c = 0; c < NC; c++) {
        size_t base = ((size_t)(bh * NC + c)) * 2048 + tid * 8;
        union { uint4 u; __bf16 h[8]; } o;
        #pragma unroll
        for (int j = 0; j < 8; j++) o.h[j] = (__bf16)S[j];
        *(uint4*)(Sprev + base) = o.u;
        float Dc = Dcs[bh * NC + c];
        const float4* dp = (const float4*)(dS + base);
        float4 d0 = dp[0], d1 = dp[1];
        S[0] = Dc * S[0] + d0.x; S[1] = Dc * S[1] + d0.y;
        S[2] = Dc * S[2] + d0.z; S[3] = Dc * S[3] + d0.w;
        S[4] = Dc * S[4] + d1.x; S[5] = Dc * S[5] + d1.y;
        S[6] = Dc * S[6] + d1.z; S[7] = Dc * S[7] + d1.w;
    }
}

// Phase C: Y += Chat @ Sprev^T for chunks 1..NC-1. Frags straight from global.
__global__ __launch_bounds__(64) void scan_xchunk(
    const __bf16* __restrict__ Chat, const __bf16* __restrict__ Sprev,
    float* __restrict__ ysD, int T) {
    int c = blockIdx.x + 1, hd = blockIdx.y, b = blockIdx.z;
    int bh = b * 8 + hd;
    int NC = T >> 6;
    int t0 = c * 64;
    int lane = threadIdx.x;
    int lm = lane & 15, q = lane >> 4;
    const __bf16* Cb = Chat + (size_t)(bh * NC + c) * 2048;
    const __bf16* Sb = Sprev + (size_t)(bh * NC + c) * 2048;
    bf16x8 cf[4], sf[4];
    #pragma unroll
    for (int t4 = 0; t4 < 4; t4++) {
        cf[t4] = *(const bf16x8*)(Cb + (t4 * 16 + lm) * 32 + q * 8);
        sf[t4] = *(const bf16x8*)(Sb + (t4 * 16 + lm) * 32 + q * 8);
    }
    #pragma unroll
    for (int ti = 0; ti < 4; ti++) {
        #pragma unroll
        for (int tp = 0; tp < 4; tp++) {
            f32x4 y = __builtin_amdgcn_mfma_f32_16x16x32_bf16(cf[ti], sf[tp], (f32x4)0.f, 0, 0, 0);
            #pragma unroll
            for (int r = 0; r < 4; r++) {
                int i = ti * 16 + q * 4 + r;
                size_t idx = ((size_t)(b * T + t0 + i)) * DINNER + hd * 64 + tp * 16 + lm;
                ysD[idx] += y[r];
            }
        }
    }
}

// y2 = rmsnorm(ysD * silu(z), gnorm) over 512 dims -> bf16; z = zx[...,:512]
__global__ void gatednorm_kernel(const float* __restrict__ ysD, const float* __restrict__ zx,
                                 const float* __restrict__ gw, __bf16* __restrict__ y2) {
    long row = blockIdx.x;
    int tid = threadIdx.x;  // 64 lanes x 8 elems
    const float* yr = ysD + row * DINNER + tid * 8;
    const float* zr = zx + row * DPROJ + tid * 8;
    float g[8];
    float ss = 0.f;
    #pragma unroll
    for (int j = 0; j < 8; j++) {
        float z = zr[j];
        float gg = yr[j] * silu_f(z);
        g[j] = gg;
        ss += gg * gg;
    }
    #pragma unroll
    for (int off = 32; off >= 1; off >>= 1) ss += __shfl_xor(ss, off);
    float rs = rsqrtf(ss * (1.f / 512.f) + 1e-5f);
    __bf16* o = y2 + row * DINNER + tid * 8;
    const float* gwp = gw + tid * 8;
    #pragma unroll
    for (int j = 0; j < 8; j++) o[j] = (__bf16)(g[j] * rs * gwp[j]);
}

__global__ void hcat_kernel(const float* __restrict__ h_f, const float* __restrict__ h_b,
                            __bf16* __restrict__ hc) {
    int idx = blockIdx.x * 256 + threadIdx.x;   // 8*128*512
    if (idx >= BSZ * TBWD * DINNER) return;
    int c = idx & 511, j = (idx >> 9) & 127, b = idx >> 16;
    float v = (c < 256) ? h_f[(b * NTOK + NVIS + j) * 256 + c]
                        : h_b[(b * TBWD + (TBWD - 1 - j)) * 256 + (c - 256)];
    hc[idx] = (__bf16)v;
}

// ---------------- launch ----------------
extern "C" void kernel_launch(void* const* d_in, const int* in_sizes, int n_in,
                              void* d_out, int out_size, void* d_ws, size_t ws_size,
                              hipStream_t stream) {
    const float* x_prefix    = (const float*)d_in[0];
    const float* y_aux       = (const float*)d_in[1];
    const float* pre_conv_w  = (const float*)d_in[2];
    const float* pre_conv_b  = (const float*)d_in[3];
    const float* patch_w     = (const float*)d_in[4];
    const float* patch_b     = (const float*)d_in[5];
    const float* mask_token  = (const float*)d_in[6];
    const float* aux_w       = (const float*)d_in[7];
    const float* aux_b       = (const float*)d_in[8];
    const float* patch_out_w = (const float*)d_in[9];
    const float* patch_out_b = (const float*)d_in[10];
    const float* w_norm[2]   = {(const float*)d_in[11], (const float*)d_in[20]};
    const float* w_inproj[2] = {(const float*)d_in[12], (const float*)d_in[21]};
    const float* w_convw[2]  = {(const float*)d_in[13], (const float*)d_in[22]};
    const float* w_convb[2]  = {(const float*)d_in[14], (const float*)d_in[23]};
    const float* w_dtb[2]    = {(const float*)d_in[15], (const float*)d_in[24]};
    const float* w_alog[2]   = {(const float*)d_in[16], (const float*)d_in[25]};
    const float* w_D[2]      = {(const float*)d_in[17], (const float*)d_in[26]};
    const float* w_gnorm[2]  = {(const float*)d_in[18], (const float*)d_in[27]};
    const float* w_outproj[2]= {(const float*)d_in[19], (const float*)d_in[28]};

    char* p = (char*)d_ws;
    auto alloc = [&](size_t bytes) { char* r = p; p += (bytes + 255) & ~255ULL; return r; };
    __bf16* A_patch  = (__bf16*)alloc((size_t)3072 * 4096 * 2);
    __bf16* Aim      = (__bf16*)alloc((size_t)BSZ * TPREF * 64 * 2);
    __bf16* WpreT    = (__bf16*)alloc((size_t)256 * 64 * 2);
    __bf16* WtT      = (__bf16*)alloc((size_t)256 * 4096 * 2);
    __bf16* inprojT  = (__bf16*)alloc((size_t)4 * 1152 * 256 * 2);
    __bf16* outprojT = (__bf16*)alloc((size_t)4 * 256 * 512 * 2);
    __bf16* poT      = (__bf16*)alloc((size_t)128 * 512 * 2);
    float*  auxb     = (float*)alloc(8 * 256 * 4);
    float*  Cp       = (float*)alloc((size_t)3072 * 256 * 4);
    float*  h_f      = (float*)alloc((size_t)BSZ * NTOK * DMODEL * 4);
    float*  h_b      = (float*)alloc((size_t)BSZ * TBWD * DMODEL * 4);
    __bf16* u        = (__bf16*)alloc((size_t)4096 * 256 * 2);
    float*  zx       = (float*)alloc((size_t)4096 * DPROJ * 4);
    float*  dtT      = (float*)alloc((size_t)64 * NTOK * 4);
    __bf16* XtT      = (__bf16*)alloc((size_t)64 * 64 * NTOK * 2);
    __bf16* BCb      = (__bf16*)alloc((size_t)BSZ * NTOK * 64 * 2);
    float*  ysD      = (float*)alloc((size_t)4096 * DINNER * 4);
    __bf16* y2       = (__bf16*)alloc((size_t)4096 * DINNER * 2);
    __bf16* hct      = (__bf16*)alloc((size_t)1024 * DINNER * 2);
    __bf16* Chat     = (__bf16*)alloc((size_t)64 * 8 * 2048 * 2);   // [bh][chunk][64i][32n]
    float*  dSb      = (float*)alloc((size_t)64 * 8 * 2048 * 4);    // [bh][chunk][64p][32n]
    __bf16* Sprev    = (__bf16*)alloc((size_t)64 * 8 * 2048 * 2);   // [bh][chunk][64p][32n]
    float*  Dcs      = (float*)alloc((size_t)64 * 8 * 4);

    // ---- weight prep ----
    prew_kernel<<<64, 256, 0, stream>>>(pre_conv_w, WpreT);
    patchw_kernel<<<4096, 256, 0, stream>>>(patch_w, WtT);
    prep_weights_kernel<<<dim3(1152, 9), 256, 0, stream>>>(
        w_inproj[0], w_inproj[1], w_outproj[0], w_outproj[1], patch_out_w,
        inprojT, outprojT, poT);
    aux_kernel<<<BSZ, 256, 0, stream>>>(y_aux, aux_w, aux_b, auxb);

    // ---- pre-conv as im2row + MFMA GEMM (silu+bf16 epilogue -> A_patch) ----
    im2row_kernel<<<(BSZ * TPREF) / 256, 256, 0, stream>>>(x_prefix, Aim);
    gemm_mfma<<<dim3(2, (BSZ * TPREF) / 128, 1), 256, 0, stream>>>(
        Aim, WpreT, (float*)A_patch, pre_conv_b, 256, 64, 256, 4);
    // ---- patch GEMM (split-K 8, atomic into zeroed Cp) ----
    hipMemsetAsync(Cp, 0, (size_t)3072 * 256 * 4, stream);
    gemm_mfma<<<dim3(2, 24, 8), 256, 0, stream>>>(A_patch, WtT, Cp, nullptr, 256, 4096, 256, 2);
    assemble_kernel<<<(BSZ * NTOK * DMODEL) / 256, 256, 0, stream>>>(Cp, patch_b, mask_token, auxb, h_f, h_b);

    for (int dir = 0; dir < 2; dir++) {
        float* h = (dir == 0) ? h_f : h_b;
        int T = (dir == 0) ? NTOK : TBWD;
        int M = BSZ * T;
        int NC = T / 64;
        for (int i = 0; i < 2; i++) {
            const __bf16* ipT = inprojT + (size_t)(dir * 2 + i) * 1152 * 256;
            const __bf16* opT = outprojT + (size_t)(dir * 2 + i) * 256 * 512;
            rmsnorm256_kernel<<<M, 64, 0, stream>>>(h, w_norm[dir] + i * 256, u);
            gemm_mfma<<<dim3(9, M / 128, 1), 256, 0, stream>>>(u, ipT, zx, nullptr, DPROJ, 256, DPROJ, 0);
            dt_kernel<<<(M * NHEADS + 255) / 256, 256, 0, stream>>>(zx, w_dtb[dir] + i * 8, dtT, T, M);
            dwconv2_kernel<<<dim3(9, T / 64, BSZ), 256, 0, stream>>>(
                zx, w_convw[dir] + i * CONVDIM * 4, w_convb[dir] + i * CONVDIM, XtT, BCb, T);
            scan_local<<<dim3(NC, NHEADS, BSZ), 64, 0, stream>>>(
                XtT, BCb, dtT, w_alog[dir] + i * 8, w_D[dir] + i * 8, ysD, Chat, dSb, Dcs, T);
            scan_combine<<<64, 256, 0, stream>>>(dSb, Dcs, Sprev, NC);
            scan_xchunk<<<dim3(NC - 1, NHEADS, BSZ), 64, 0, stream>>>(Chat, Sprev, ysD, T);
            gatednorm_kernel<<<M, 64, 0, stream>>>(ysD, zx, w_gnorm[dir] + i * DINNER, y2);
            gemm_mfma<<<dim3(2, M / 128, 2), 256, 0, stream>>>(y2, opT, h, nullptr, 256, 512, 256, 2);
        }
    }

    hcat_kernel<<<(BSZ * TBWD * DINNER) / 256, 256, 0, stream>>>(h_f, h_b, hct);
    biasout_kernel<<<(BSZ * TBWD * 128) / 256, 256, 0, stream>>>(patch_out_b, (float*)d_out);
    gemm_mfma<<<dim3(1, 8, 4), 256, 0, stream>>>(hct, poT, (float*)d_out, nullptr, 128, 512, 128, 2);
}